// Round 18
// baseline (93.799 us; speedup 1.0000x reference)
//
#include <hip/hip_runtime.h>
#include <hip/hip_bf16.h>

#define BB 4
#define DEPTH 160
#define CC 96
#define NN 2560          // DEPTH*16
#define NHH 4
#define HD 24
#define THETA 0.6f
#define BN_EPS 1e-5f

typedef __attribute__((ext_vector_type(4))) float f32x4;
typedef __attribute__((ext_vector_type(8))) short s16x8;
typedef __attribute__((ext_vector_type(4))) short s16x4;
typedef __attribute__((ext_vector_type(2))) unsigned u32x2;
typedef __attribute__((ext_vector_type(4))) unsigned u32x4;

#if __has_builtin(__builtin_amdgcn_exp2f)
#define EXP2(x) __builtin_amdgcn_exp2f(x)
#else
#define EXP2(x) exp2f(x)
#endif

// ---------------------------------------------------------------------------
// Workspace layout (float slots):
//   wq_b  : bf16 [tap][oc][ic] 27*96*96 shorts  -> 124416 slots (r10 layout)
//   wk_b  : 124416
//   wv_b  : bf16 [oc][ic] 9216 shorts -> 4608
//   bias_q: 96, bias_k: 96 (fp32)
//   att   : fp32 [b][n][96]                     -> 983040
//   Qb    : bf16 [bh][n][32] (hd 24..31 zeroed) -> 655360
//   Kb    : bf16 [bh][n][32]                    -> 655360
//   Vtp   : bf16 [bh][tile][s*2+dh][16 dims][32 slots] — per-64-key-tile blocked
//   wo_b  : bf16 frag-blocked [oct 6][icb 3][j16 x 32ic] -> 4608 slots
// ---------------------------------------------------------------------------
#define WS_WQ   0
#define WS_WK   124416
#define WS_WV   248832
#define WS_BQ   253440
#define WS_BK   253536
#define WS_ATT  253632
#define WS_QB   1236672
#define WS_KB   1892032
#define WS_VT   2547392
#define WS_WO   3202752

__device__ __forceinline__ short f2bf(float f) {
    unsigned u = __float_as_uint(f);
    u += 0x7fffu + ((u >> 16) & 1u);
    return (short)(u >> 16);
}
__device__ __forceinline__ unsigned bf16pk(float lo, float hi) {
    unsigned r;
    asm("v_cvt_pk_bf16_f32 %0, %1, %2" : "=v"(r) : "v"(lo), "v"(hi));
    return r;
}
// PV slot of key n within its 64-token tile (bit5 = s-half kept, low 5 permuted
// so the P B-fragment is the lane's own QK^T output).
__device__ __forceinline__ int vslot(int n) {
    return (n & 32) | (((n >> 2) & 3) << 3) | (((n >> 4) & 1) << 2) | (n & 3);
}

// Fold TCDC center-tap correction + BN scale into conv weights; bf16 [tap][oc][ic].
// The Q-instance also converts the 1x1x1 V weights (wv/wv_b non-null).
__global__ void prep_w(const float* __restrict__ w, const float* __restrict__ gamma,
                       const float* __restrict__ beta, const float* __restrict__ mean,
                       const float* __restrict__ var, short* __restrict__ w_eff,
                       float* __restrict__ bias,
                       const float* __restrict__ wv, short* __restrict__ wv_b) {
    int oc = blockIdx.x;
    int ic = threadIdx.x;
    if (ic >= CC) return;
    float scale = gamma[oc] * rsqrtf(var[oc] + BN_EPS);
    if (ic == 0) bias[oc] = beta[oc] - mean[oc] * scale;
    const float* wp = w + (oc * CC + ic) * 27;
    float kdiff = 0.f;
#pragma unroll
    for (int t = 0; t < 9; ++t) kdiff += wp[t] + wp[18 + t];
#pragma unroll
    for (int t = 0; t < 27; ++t) {
        float v = wp[t];
        if (t == 13) v -= THETA * kdiff;     // center tap (1,1,1)
        w_eff[t * (CC * CC) + oc * CC + ic] = f2bf(v * scale);
    }
    if (wv_b) wv_b[oc * CC + ic] = f2bf(wv[oc * CC + ic]);
}

// wo -> fragment-blocked bf16 [oct][icb][(oc&15)*32 + (ic&31)]
__global__ void prep_wo(const float* __restrict__ wo, short* __restrict__ wo_b) {
    int i = blockIdx.x * 256 + threadIdx.x;
    if (i < CC * CC) {
        int oc = i / CC, ic = i % CC;
        wo_b[(((oc >> 4) * 3 + (ic >> 5)) << 9) + (oc & 15) * 32 + (ic & 31)] = f2bf(wo[i]);
    }
}

#define MFMA16(A, B, C) __builtin_amdgcn_mfma_f32_16x16x32_bf16(A, B, C, 0, 0, 0)

// Tap-range conv body with 1-deep register weight prefetch (r15-proven).
template<int TB, int TE>
__device__ __forceinline__ void conv_taps(
        const short* __restrict__ wqlane, const short* __restrict__ wklane,
        const short* __restrict__ wvlane, const short* xs,
        int hj, int wj, int g,
        f32x4& accQA, f32x4& accQB, f32x4& accKA, f32x4& accKB,
        f32x4& avA, f32x4& avB) {
    s16x8 wqc[3], wkc[3], wqn[3], wkn[3];
#pragma unroll
    for (int icb = 0; icb < 3; ++icb) {
        wqc[icb] = *(const s16x8*)(wqlane + TB * (CC * CC) + icb * 32);
        wkc[icb] = *(const s16x8*)(wklane + TB * (CC * CC) + icb * 32);
    }
#pragma unroll
    for (int tap = TB; tap < TE; ++tap) {
        if (tap < TE - 1) {
#pragma unroll
            for (int icb = 0; icb < 3; ++icb) {
                wqn[icb] = *(const s16x8*)(wqlane + (tap + 1) * (CC * CC) + icb * 32);
                wkn[icb] = *(const s16x8*)(wklane + (tap + 1) * (CC * CC) + icb * 32);
            }
        }
        const int kd = tap / 9, kh = (tap / 3) % 3, kw = tap % 3;
        const int hh = hj + kh - 1, ww = wj + kw - 1;
        const bool valid = ((unsigned)hh < 4u) && ((unsigned)ww < 4u);
        const int rA = valid ? (kd * 16 + hh * 4 + ww) : 64;       // slice t=0
        const int rB = valid ? ((1 + kd) * 16 + hh * 4 + ww) : 64; // slice t=1
        const short* xrA = &xs[rA * 104 + 8 * g];
        const short* xrB = &xs[rB * 104 + 8 * g];
#pragma unroll
        for (int icb = 0; icb < 3; ++icb) {
            s16x8 afA = *(const s16x8*)(xrA + icb * 32);
            s16x8 afB = *(const s16x8*)(xrB + icb * 32);
            accQA = MFMA16(afA, wqc[icb], accQA);
            accQB = MFMA16(afB, wqc[icb], accQB);
            accKA = MFMA16(afA, wkc[icb], accKA);
            accKB = MFMA16(afB, wkc[icb], accKB);
            if (tap == 13) {   // V rides the center tap's A-frags
                s16x8 bv = *(const s16x8*)(wvlane + icb * 32);
                avA = MFMA16(afA, bv, avA);
                avB = MFMA16(afB, bv, avB);
            }
        }
        if (tap < TE - 1) {
#pragma unroll
            for (int icb = 0; icb < 3; ++icb) {
                wqc[icb] = wqn[icb];
                wkc[icb] = wkn[icb];
            }
        }
    }
}

// MFMA im2col conv — TAP-SPLIT x2: block = (2 depth slices) x (oc-half);
// 6 waves = half(2) x oct(3). Half 0: taps 0-13 (incl. V tap 13); half 1:
// taps 14-26. Serial weight-load chain per wave HALVES (14 vs 27) and TLP
// doubles (3.75 waves/SIMD) at UNCHANGED weight L2 traffic — attacking the
// r12/r14-measured latency exposure (all pipes <8% busy). fp32 partial-sum
// combine via one LDS exchange at the end; epilogue on half-0 waves only.
__global__ __launch_bounds__(384) void qkv_conv(
        const float* __restrict__ x, const short* __restrict__ wq_b,
        const short* __restrict__ wk_b, const short* __restrict__ wv_b,
        const float* __restrict__ bias_q, const float* __restrict__ bias_k,
        const float* __restrict__ sgp,
        short* __restrict__ Qb, short* __restrict__ Kb, short* __restrict__ Vtp) {
    __shared__ __align__(16) short xs[65 * 104];    // 13.5 KB
    __shared__ __align__(16) float comb[3][64][16]; // 12 KB
    const int b = blockIdx.y;
    const int d0 = blockIdx.x * 2;
    const int z = blockIdx.z;                       // oc-half
    const int tid = threadIdx.x;

    // stage x: 4 slices (d0-1 .. d0+2), f32 -> bf16 via cvt_pk; 1536 chunks
#pragma unroll
    for (int k = 0; k < 4; ++k) {
        int c = tid + k * 384;
        int row = c / 24, ic0 = (c % 24) * 4;
        int dg = d0 - 1 + (row >> 4), pos = row & 15;
        u32x2 o = {0u, 0u};
        if (dg >= 0 && dg < DEPTH) {
            f32x4 v = *(const f32x4*)(x + ((size_t)(b * NN + dg * 16 + pos)) * CC + ic0);
            o[0] = bf16pk(v[0], v[1]);
            o[1] = bf16pk(v[2], v[3]);
        }
        *(u32x2*)&xs[row * 104 + ic0] = o;
    }
    if (tid < 26) *(u32x2*)&xs[64 * 104 + tid * 4] = (u32x2){0u, 0u};
    __syncthreads();

    const int w = tid >> 6, l = tid & 63;
    const int oct = w % 3, half = w / 3;
    const int j = l & 15, g = l >> 4;
    const int oc0 = z * 48 + oct * 16;
    const int hj = j >> 2, wj = j & 3;

    const short* wqlane = wq_b + (oc0 + j) * CC + 8 * g;
    const short* wklane = wk_b + (oc0 + j) * CC + 8 * g;
    const short* wvlane = wv_b + (oc0 + j) * CC + 8 * g;

    f32x4 accQA = {0,0,0,0}, accQB = {0,0,0,0};
    f32x4 accKA = {0,0,0,0}, accKB = {0,0,0,0};
    f32x4 avA   = {0,0,0,0}, avB   = {0,0,0,0};

    if (half == 0)
        conv_taps<0, 14>(wqlane, wklane, wvlane, xs, hj, wj, g,
                         accQA, accQB, accKA, accKB, avA, avB);
    else
        conv_taps<14, 27>(wqlane, wklane, wvlane, xs, hj, wj, g,
                          accQA, accQB, accKA, accKB, avA, avB);

    // cross-half combine (fp32 partial sums)
    if (half == 1) {
        float* cp = comb[oct][l];
        *(f32x4*)(cp)      = accQA;
        *(f32x4*)(cp + 4)  = accQB;
        *(f32x4*)(cp + 8)  = accKA;
        *(f32x4*)(cp + 12) = accKB;
    }
    __syncthreads();
    if (half != 0) return;
    {
        const float* cp = comb[oct][l];
        accQA += *(const f32x4*)(cp);
        accQB += *(const f32x4*)(cp + 4);
        accKA += *(const f32x4*)(cp + 8);
        accKB += *(const f32x4*)(cp + 12);
    }

    // epilogue (half-0 waves; identical lane mapping to r16)
    const float qs = 1.4426950408889634f / sgp[0];
    const int oc = oc0 + j, h = oc / HD, hd = oc % HD;
    const float bq_ = bias_q[oc], bk_ = bias_k[oc];
    const size_t headbase = (size_t)(b * NHH + h) * NN;
    short* QpA = Qb + (headbase + (d0 + 0) * 16 + 4 * g) * 32 + hd;
    short* QpB = Qb + (headbase + (d0 + 1) * 16 + 4 * g) * 32 + hd;
    short* KpA = Kb + (headbase + (d0 + 0) * 16 + 4 * g) * 32 + hd;
    short* KpB = Kb + (headbase + (d0 + 1) * 16 + 4 * g) * 32 + hd;
#pragma unroll
    for (int r = 0; r < 4; ++r) {
        QpA[r * 32] = f2bf((accQA[r] + bq_) * qs);
        QpB[r * 32] = f2bf((accQB[r] + bq_) * qs);
        KpA[r * 32] = f2bf(accKA[r] + bk_);
        KpB[r * 32] = f2bf(accKB[r] + bk_);
    }
    {
        short* Vb = Vtp + (size_t)(b * NHH + h) * (NN * 32);
        const int dh = hd >> 4, dj = hd & 15;
#pragma unroll
        for (int r = 0; r < 4; ++r) {
            int nA = d0 * 16 + 4 * g + r;
            int nB = nA + 16;
            int wA = vslot(nA & 63), wB = vslot(nB & 63);
            Vb[(nA >> 6) * 2048 + ((wA >> 5) * 2 + dh) * 512 + dj * 32 + (wA & 31)] = f2bf(avA[r]);
            Vb[(nB >> 6) * 2048 + ((wB >> 5) * 2 + dh) * 512 + dj * 32 + (wB & 31)] = f2bf(avB[r]);
        }
    }
    if (z == 0 && oct == 0) {
        const int n = (d0 + ((l >> 4) & 1)) * 16 + (l & 15);
        const s16x8 z8 = {0, 0, 0, 0, 0, 0, 0, 0};
#pragma unroll
        for (int it = 0; it < 2; ++it) {
            int h2 = (l >> 5) + 2 * it;
            *(s16x8*)(Qb + ((size_t)(b * NHH + h2) * NN + n) * 32 + 24) = z8;
            *(s16x8*)(Kb + ((size_t)(b * NHH + h2) * NN + n) * 32 + 24) = z8;
        }
        const int wN = vslot(n & 63);
#pragma unroll
        for (int it2 = 0; it2 < 2; ++it2) {
            int h3 = it2 * 2 + (l >> 5);
            short* pb = Vtp + (size_t)(b * NHH + h3) * (NN * 32)
                      + (n >> 6) * 2048 + ((wN >> 5) * 2 + 1) * 512 + (wN & 31);
#pragma unroll
            for (int dj = 8; dj < 16; ++dj)
                pb[dj * 32] = 0;
        }
    }
}

// MFMA flash attention — r10 (proven, byte-identical).
#define SOFTTILE(S0, S1, S2, S3, MX, LP, OA, OB, P0, P1) {                      \
    float v0 = fmaxf(fmaxf(S0[0], S0[1]), fmaxf(S0[2], S0[3]));                 \
    float v1 = fmaxf(fmaxf(S1[0], S1[1]), fmaxf(S1[2], S1[3]));                 \
    float v2 = fmaxf(fmaxf(S2[0], S2[1]), fmaxf(S2[2], S2[3]));                 \
    float v3 = fmaxf(fmaxf(S3[0], S3[1]), fmaxf(S3[2], S3[3]));                 \
    float vmx = fmaxf(fmaxf(v0, v1), fmaxf(v2, v3));                            \
    vmx = fmaxf(vmx, __shfl_xor(vmx, 16));                                      \
    vmx = fmaxf(vmx, __shfl_xor(vmx, 32));                                      \
    float nm = fmaxf(MX, vmx);                                                  \
    float sc = EXP2(MX - nm);                                                   \
    MX = nm;                                                                    \
    LP *= sc; OA *= sc; OB *= sc;                                               \
    float p00 = EXP2(S0[0] - MX), p01 = EXP2(S0[1] - MX);                       \
    float p02 = EXP2(S0[2] - MX), p03 = EXP2(S0[3] - MX);                       \
    float p10 = EXP2(S1[0] - MX), p11 = EXP2(S1[1] - MX);                       \
    float p12 = EXP2(S1[2] - MX), p13 = EXP2(S1[3] - MX);                       \
    float p20 = EXP2(S2[0] - MX), p21 = EXP2(S2[1] - MX);                       \
    float p22 = EXP2(S2[2] - MX), p23 = EXP2(S2[3] - MX);                       \
    float p30 = EXP2(S3[0] - MX), p31 = EXP2(S3[1] - MX);                       \
    float p32 = EXP2(S3[2] - MX), p33 = EXP2(S3[3] - MX);                       \
    LP += (((p00 + p01) + (p02 + p03)) + ((p10 + p11) + (p12 + p13)))           \
        + (((p20 + p21) + (p22 + p23)) + ((p30 + p31) + (p32 + p33)));          \
    u32x4 w0_ = { bf16pk(p00, p01), bf16pk(p02, p03),                           \
                  bf16pk(p10, p11), bf16pk(p12, p13) };                         \
    u32x4 w1_ = { bf16pk(p20, p21), bf16pk(p22, p23),                           \
                  bf16pk(p30, p31), bf16pk(p32, p33) };                         \
    P0 = __builtin_bit_cast(s16x8, w0_);                                        \
    P1 = __builtin_bit_cast(s16x8, w1_);                                        \
}

__global__ __launch_bounds__(256) void attn_kernel(
        const short* __restrict__ Qb, const short* __restrict__ Kb,
        const short* __restrict__ Vtp, float* __restrict__ att) {
    __shared__ __align__(16) float comb[3][64][20];
    const int bh = blockIdx.x & 15;            // pins bh pairs per XCD for L2 reuse
    const int q0 = (blockIdx.x >> 4) * 32;
    const int b = bh >> 2, h = bh & 3;
    const int tid = threadIdx.x, wvid = tid >> 6, l = tid & 63;
    const int j = l & 15, g = l >> 4;

    const s16x8 qf0 = *(const s16x8*)(Qb + ((size_t)bh * NN + q0 + j) * 32 + 8 * g);
    const s16x8 qf1 = *(const s16x8*)(Qb + ((size_t)bh * NN + q0 + 16 + j) * 32 + 8 * g);
    const short* Kbase = Kb  + (size_t)bh * NN * 32 + (size_t)j * 32 + 8 * g;
    const short* Vbase = Vtp + (size_t)bh * NN * 32 + (size_t)j * 32 + 8 * g;

    f32x4 oA0 = {0,0,0,0}, oB0 = {0,0,0,0};    // q-tile 0: O^T dims 4g.. / 16+4g..
    f32x4 oA1 = {0,0,0,0}, oB1 = {0,0,0,0};    // q-tile 1
    float mx0 = -1e30f, lp0 = 0.f, mx1 = -1e30f, lp1 = 0.f;
    const f32x4 z = {0,0,0,0};

    const int tbeg = wvid * (NN / 4);
    const int tend = tbeg + NN / 4;            // 640 keys, 10 tiles per wave

    for (int t0 = tbeg; t0 < tend; t0 += 64) {
        const short* kp = Kbase + (size_t)t0 * 32;
        s16x8 k0 = *(const s16x8*)(kp);
        s16x8 k1 = *(const s16x8*)(kp + 512);
        s16x8 k2 = *(const s16x8*)(kp + 1024);
        s16x8 k3 = *(const s16x8*)(kp + 1536);
        const short* vp = Vbase + (size_t)t0 * 32;     // tile base: t0/64*2048
        s16x8 vA0 = *(const s16x8*)(vp);               // (s0,d0)
        s16x8 vB0 = *(const s16x8*)(vp + 512);         // (s0,d1)
        s16x8 vA1 = *(const s16x8*)(vp + 1024);        // (s1,d0)
        s16x8 vB1 = *(const s16x8*)(vp + 1536);        // (s1,d1)

        f32x4 s0 = __builtin_amdgcn_mfma_f32_16x16x32_bf16(k0, qf0, z, 0, 0, 0);
        f32x4 s1 = __builtin_amdgcn_mfma_f32_16x16x32_bf16(k1, qf0, z, 0, 0, 0);
        f32x4 s2 = __builtin_amdgcn_mfma_f32_16x16x32_bf16(k2, qf0, z, 0, 0, 0);
        f32x4 s3 = __builtin_amdgcn_mfma_f32_16x16x32_bf16(k3, qf0, z, 0, 0, 0);
        s16x8 P00, P01;
        SOFTTILE(s0, s1, s2, s3, mx0, lp0, oA0, oB0, P00, P01)

        f32x4 t0s = __builtin_amdgcn_mfma_f32_16x16x32_bf16(k0, qf1, z, 0, 0, 0);
        f32x4 t1s = __builtin_amdgcn_mfma_f32_16x16x32_bf16(k1, qf1, z, 0, 0, 0);
        f32x4 t2s = __builtin_amdgcn_mfma_f32_16x16x32_bf16(k2, qf1, z, 0, 0, 0);
        f32x4 t3s = __builtin_amdgcn_mfma_f32_16x16x32_bf16(k3, qf1, z, 0, 0, 0);
        s16x8 P10, P11;
        SOFTTILE(t0s, t1s, t2s, t3s, mx1, lp1, oA1, oB1, P10, P11)

        oA0 = __builtin_amdgcn_mfma_f32_16x16x32_bf16(vA0, P00, oA0, 0, 0, 0);
        oA0 = __builtin_amdgcn_mfma_f32_16x16x32_bf16(vA1, P01, oA0, 0, 0, 0);
        oB0 = __builtin_amdgcn_mfma_f32_16x16x32_bf16(vB0, P00, oB0, 0, 0, 0);
        oB0 = __builtin_amdgcn_mfma_f32_16x16x32_bf16(vB1, P01, oB0, 0, 0, 0);
        oA1 = __builtin_amdgcn_mfma_f32_16x16x32_bf16(vA0, P10, oA1, 0, 0, 0);
        oA1 = __builtin_amdgcn_mfma_f32_16x16x32_bf16(vA1, P11, oA1, 0, 0, 0);
        oB1 = __builtin_amdgcn_mfma_f32_16x16x32_bf16(vB0, P10, oB1, 0, 0, 0);
        oB1 = __builtin_amdgcn_mfma_f32_16x16x32_bf16(vB1, P11, oB1, 0, 0, 0);
    }

    // row-sum lp across the 4 g-lanes
    lp0 += __shfl_xor(lp0, 16); lp0 += __shfl_xor(lp0, 32);
    lp1 += __shfl_xor(lp1, 16); lp1 += __shfl_xor(lp1, 32);

    if (wvid != 0) {
        float* cp = comb[wvid - 1][l];
        cp[0] = mx0; cp[1] = lp0; cp[2] = mx1; cp[3] = lp1;
        *(f32x4*)(cp + 4)  = oA0;
        *(f32x4*)(cp + 8)  = oB0;
        *(f32x4*)(cp + 12) = oA1;
        *(f32x4*)(cp + 16) = oB1;
    }
    __syncthreads();
    if (wvid != 0) return;

#pragma unroll
    for (int wv = 0; wv < 3; ++wv) {
        const float* cp = comb[wv][l];
        {
            float mb = cp[0], lb = cp[1];
            f32x4 oAb = *(const f32x4*)(cp + 4);
            f32x4 oBb = *(const f32x4*)(cp + 8);
            float mm = fmaxf(mx0, mb);
            float sa = EXP2(mx0 - mm), sb = EXP2(mb - mm);
            mx0 = mm;
            lp0 = lp0 * sa + lb * sb;
            oA0 = oA0 * sa + oAb * sb;
            oB0 = oB0 * sa + oBb * sb;
        }
        {
            float mb = cp[2], lb = cp[3];
            f32x4 oAb = *(const f32x4*)(cp + 12);
            f32x4 oBb = *(const f32x4*)(cp + 16);
            float mm = fmaxf(mx1, mb);
            float sa = EXP2(mx1 - mm), sb = EXP2(mb - mm);
            mx1 = mm;
            lp1 = lp1 * sa + lb * sb;
            oA1 = oA1 * sa + oAb * sb;
            oB1 = oB1 * sa + oBb * sb;
        }
    }

    const float rl0 = 1.f / lp0, rl1 = 1.f / lp1;
    f32x4 rA0 = oA0 * rl0, rB0 = oB0 * rl0;
    f32x4 rA1 = oA1 * rl1, rB1 = oB1 * rl1;

    float* op0 = att + ((size_t)b * NN + q0 + j) * CC + h * HD;
    float* op1 = att + ((size_t)b * NN + q0 + 16 + j) * CC + h * HD;
    *(f32x4*)(op0 + 4 * g) = rA0;
    *(f32x4*)(op1 + 4 * g) = rA1;
    if (g < 2) {
        *(f32x4*)(op0 + 16 + 4 * g) = rB0;
        *(f32x4*)(op1 + 16 + 4 * g) = rB1;
    }
}

// MFMA out-projection — r16 (proven, byte-identical).
__global__ __launch_bounds__(256) void proj_kernel(
        const float* __restrict__ att, const short* __restrict__ wo_b,
        const float* __restrict__ bo, float* __restrict__ out) {
    __shared__ __align__(16) short als[64 * 104];
    const int t0 = blockIdx.x * 64;
    const int tid = threadIdx.x;
#pragma unroll
    for (int k = 0; k < 6; ++k) {
        int c = tid + k * 256;                      // 1536 chunks
        int row = c / 24, ic0 = (c % 24) * 4;
        f32x4 v = *(const f32x4*)(att + (size_t)(t0 + row) * CC + ic0);
        u32x2 o = { bf16pk(v[0], v[1]), bf16pk(v[2], v[3]) };
        *(u32x2*)&als[row * 104 + ic0] = o;
    }
    __syncthreads();

    const int w = tid >> 6, l = tid & 63;
    const int j = l & 15, g = l >> 4;
    const short* ap = &als[(w * 16 + j) * 104 + 8 * g];
    s16x8 a0 = *(const s16x8*)(ap);
    s16x8 a1 = *(const s16x8*)(ap + 32);
    s16x8 a2 = *(const s16x8*)(ap + 64);
    const f32x4 zz = {0, 0, 0, 0};
    float* ob = out + (size_t)(t0 + w * 16 + 4 * g) * CC + j;
#pragma unroll
    for (int oct = 0; oct < 6; ++oct) {
        const short* wp = wo_b + oct * 3 * 512 + j * 32 + 8 * g;
        f32x4 acc = zz;
        acc = __builtin_amdgcn_mfma_f32_16x16x32_bf16(a0, *(const s16x8*)(wp),        acc, 0, 0, 0);
        acc = __builtin_amdgcn_mfma_f32_16x16x32_bf16(a1, *(const s16x8*)(wp + 512),  acc, 0, 0, 0);
        acc = __builtin_amdgcn_mfma_f32_16x16x32_bf16(a2, *(const s16x8*)(wp + 1024), acc, 0, 0, 0);
        const float bb = bo[oct * 16 + j];
#pragma unroll
        for (int r = 0; r < 4; ++r)
            ob[(size_t)r * CC + oct * 16] = acc[r] + bb;
    }
}

extern "C" void kernel_launch(void* const* d_in, const int* in_sizes, int n_in,
                              void* d_out, int out_size, void* d_ws, size_t ws_size,
                              hipStream_t stream) {
    const float* x     = (const float*)d_in[0];
    const float* sg    = (const float*)d_in[1];
    const float* wq    = (const float*)d_in[2];
    const float* bnq_g = (const float*)d_in[3];
    const float* bnq_b = (const float*)d_in[4];
    const float* bnq_m = (const float*)d_in[5];
    const float* bnq_v = (const float*)d_in[6];
    const float* wk    = (const float*)d_in[7];
    const float* bnk_g = (const float*)d_in[8];
    const float* bnk_b = (const float*)d_in[9];
    const float* bnk_m = (const float*)d_in[10];
    const float* bnk_v = (const float*)d_in[11];
    const float* wv    = (const float*)d_in[12];
    const float* wo    = (const float*)d_in[13];
    const float* bo    = (const float*)d_in[14];

    float* ws = (float*)d_ws;
    short* wq_b   = (short*)(ws + WS_WQ);
    short* wk_b   = (short*)(ws + WS_WK);
    short* wv_b   = (short*)(ws + WS_WV);
    float* bias_q = ws + WS_BQ;
    float* bias_k = ws + WS_BK;
    float* attw   = ws + WS_ATT;
    short* Qb     = (short*)(ws + WS_QB);
    short* Kb     = (short*)(ws + WS_KB);
    short* Vtp    = (short*)(ws + WS_VT);
    short* wo_b   = (short*)(ws + WS_WO);

    prep_w<<<dim3(CC), dim3(128), 0, stream>>>(wq, bnq_g, bnq_b, bnq_m, bnq_v, wq_b, bias_q,
                                               wv, wv_b);
    prep_w<<<dim3(CC), dim3(128), 0, stream>>>(wk, bnk_g, bnk_b, bnk_m, bnk_v, wk_b, bias_k,
                                               nullptr, nullptr);
    prep_wo<<<dim3(36), dim3(256), 0, stream>>>(wo, wo_b);

    qkv_conv<<<dim3(DEPTH / 2, BB, 2), dim3(384), 0, stream>>>(
        x, wq_b, wk_b, wv_b, bias_q, bias_k, sg, Qb, Kb, Vtp);

    attn_kernel<<<dim3(NN / 32 * 16), dim3(256), 0, stream>>>(Qb, Kb, Vtp, attw);

    proj_kernel<<<dim3(BB * NN / 64), dim3(256), 0, stream>>>(attw, wo_b, bo, (float*)d_out);
}

// Round 19
// 78.276 us; speedup vs baseline: 1.1983x; 1.1983x over previous
//
#include <hip/hip_runtime.h>
#include <hip/hip_bf16.h>

#define BB 4
#define DEPTH 160
#define CC 96
#define NN 2560          // DEPTH*16
#define NHH 4
#define HD 24
#define THETA 0.6f
#define BN_EPS 1e-5f

typedef __attribute__((ext_vector_type(4))) float f32x4;
typedef __attribute__((ext_vector_type(8))) short s16x8;
typedef __attribute__((ext_vector_type(4))) short s16x4;
typedef __attribute__((ext_vector_type(2))) unsigned u32x2;
typedef __attribute__((ext_vector_type(4))) unsigned u32x4;

#if __has_builtin(__builtin_amdgcn_exp2f)
#define EXP2(x) __builtin_amdgcn_exp2f(x)
#else
#define EXP2(x) exp2f(x)
#endif

// ---------------------------------------------------------------------------
// Workspace layout (float slots):
//   wq_b  : bf16 [tap][oc][ic] 27*96*96 shorts  -> 124416 slots (r10 layout)
//   wk_b  : 124416
//   wv_b  : bf16 [oc][ic] 9216 shorts -> 4608
//   bias_q: 96, bias_k: 96 (fp32)
//   att   : fp32 [b][n][96]                     -> 983040
//   Qb    : bf16 [bh][n][32] (hd 24..31 zeroed) -> 655360
//   Kb    : bf16 [bh][n][32]                    -> 655360
//   Vtp   : bf16 [bh][tile][s*2+dh][16 dims][32 slots] — per-64-key-tile blocked
//   wo_b  : bf16 frag-blocked [oct 6][icb 3][j16 x 32ic] -> 4608 slots
// ---------------------------------------------------------------------------
#define WS_WQ   0
#define WS_WK   124416
#define WS_WV   248832
#define WS_BQ   253440
#define WS_BK   253536
#define WS_ATT  253632
#define WS_QB   1236672
#define WS_KB   1892032
#define WS_VT   2547392
#define WS_WO   3202752

__device__ __forceinline__ short f2bf(float f) {
    unsigned u = __float_as_uint(f);
    u += 0x7fffu + ((u >> 16) & 1u);
    return (short)(u >> 16);
}
__device__ __forceinline__ unsigned bf16pk(float lo, float hi) {
    unsigned r;
    asm("v_cvt_pk_bf16_f32 %0, %1, %2" : "=v"(r) : "v"(lo), "v"(hi));
    return r;
}
// PV slot of key n within its 64-token tile (bit5 = s-half kept, low 5 permuted
// so the P B-fragment is the lane's own QK^T output).
__device__ __forceinline__ int vslot(int n) {
    return (n & 32) | (((n >> 2) & 3) << 3) | (((n >> 4) & 1) << 2) | (n & 3);
}

// Fold TCDC center-tap correction + BN scale into conv weights; bf16 [tap][oc][ic].
// The Q-instance also converts the 1x1x1 V weights (wv/wv_b non-null).
__global__ void prep_w(const float* __restrict__ w, const float* __restrict__ gamma,
                       const float* __restrict__ beta, const float* __restrict__ mean,
                       const float* __restrict__ var, short* __restrict__ w_eff,
                       float* __restrict__ bias,
                       const float* __restrict__ wv, short* __restrict__ wv_b) {
    int oc = blockIdx.x;
    int ic = threadIdx.x;
    if (ic >= CC) return;
    float scale = gamma[oc] * rsqrtf(var[oc] + BN_EPS);
    if (ic == 0) bias[oc] = beta[oc] - mean[oc] * scale;
    const float* wp = w + (oc * CC + ic) * 27;
    float kdiff = 0.f;
#pragma unroll
    for (int t = 0; t < 9; ++t) kdiff += wp[t] + wp[18 + t];
#pragma unroll
    for (int t = 0; t < 27; ++t) {
        float v = wp[t];
        if (t == 13) v -= THETA * kdiff;     // center tap (1,1,1)
        w_eff[t * (CC * CC) + oc * CC + ic] = f2bf(v * scale);
    }
    if (wv_b) wv_b[oc * CC + ic] = f2bf(wv[oc * CC + ic]);
}

// wo -> fragment-blocked bf16 [oct][icb][(oc&15)*32 + (ic&31)]
__global__ void prep_wo(const float* __restrict__ wo, short* __restrict__ wo_b) {
    int i = blockIdx.x * 256 + threadIdx.x;
    if (i < CC * CC) {
        int oc = i / CC, ic = i % CC;
        wo_b[(((oc >> 4) * 3 + (ic >> 5)) << 9) + (oc & 15) * 32 + (ic & 31)] = f2bf(wo[i]);
    }
}

#define MFMA16(A, B, C) __builtin_amdgcn_mfma_f32_16x16x32_bf16(A, B, C, 0, 0, 0)

// MFMA im2col conv — r16 structure (best measured) with a 2-TAP-DEEP register
// weight pipeline. Block = (2 depth slices) x (oc-half); 3 waves = oct(3).
// Each wave computes Q+K+V for one oc-tile across both token slices.
// 3-slot ring (cur/+1/+2): 12 weight loads in flight -> prefetch distance
// ~340 cy of MFMA issue >= measured L2 latency (r12/r14: all pipes <8% busy
// with the 1-deep pipeline whose ~170 cy distance was insufficient).
__global__ __launch_bounds__(192) void qkv_conv(
        const float* __restrict__ x, const short* __restrict__ wq_b,
        const short* __restrict__ wk_b, const short* __restrict__ wv_b,
        const float* __restrict__ bias_q, const float* __restrict__ bias_k,
        const float* __restrict__ sgp,
        short* __restrict__ Qb, short* __restrict__ Kb, short* __restrict__ Vtp) {
    __shared__ __align__(16) short xs[65 * 104];   // 64 rows + zero row, stride 104
    const int b = blockIdx.y;
    const int d0 = blockIdx.x * 2;
    const int z = blockIdx.z;                       // oc-half
    const int tid = threadIdx.x;

    // stage 4 slices (d0-1 .. d0+2), f32 -> bf16 via cvt_pk; 1536 chunks
#pragma unroll
    for (int k = 0; k < 8; ++k) {
        int c = tid + k * 192;
        int row = c / 24, ic0 = (c % 24) * 4;
        int dg = d0 - 1 + (row >> 4), pos = row & 15;
        u32x2 o = {0u, 0u};
        if (dg >= 0 && dg < DEPTH) {
            f32x4 v = *(const f32x4*)(x + ((size_t)(b * NN + dg * 16 + pos)) * CC + ic0);
            o[0] = bf16pk(v[0], v[1]);
            o[1] = bf16pk(v[2], v[3]);
        }
        *(u32x2*)&xs[row * 104 + ic0] = o;
    }
    if (tid < 26) *(u32x2*)&xs[64 * 104 + tid * 4] = (u32x2){0u, 0u};
    __syncthreads();

    const int w  = tid >> 6, l = tid & 63;          // w = oct
    const int j  = l & 15, g = l >> 4;
    const int oc0 = z * 48 + w * 16;
    const int hj = j >> 2, wj = j & 3;

    const short* wqlane = wq_b + (oc0 + j) * CC + 8 * g;
    const short* wklane = wk_b + (oc0 + j) * CC + 8 * g;
    const short* wvlane = wv_b + (oc0 + j) * CC + 8 * g;

    f32x4 accQA = {0,0,0,0}, accQB = {0,0,0,0};
    f32x4 accKA = {0,0,0,0}, accKB = {0,0,0,0};
    f32x4 avA   = {0,0,0,0}, avB   = {0,0,0,0};

    // 3-slot register ring: taps t (compute), t+1, t+2 (in flight)
    s16x8 wq0[3], wk0[3], wq1[3], wk1[3], wq2[3], wk2[3];
#pragma unroll
    for (int icb = 0; icb < 3; ++icb) {
        wq0[icb] = *(const s16x8*)(wqlane + 0 * (CC * CC) + icb * 32);
        wk0[icb] = *(const s16x8*)(wklane + 0 * (CC * CC) + icb * 32);
        wq1[icb] = *(const s16x8*)(wqlane + 1 * (CC * CC) + icb * 32);
        wk1[icb] = *(const s16x8*)(wklane + 1 * (CC * CC) + icb * 32);
    }

#pragma unroll
    for (int tap = 0; tap < 27; ++tap) {
        // issue tap+2's loads first (land while taps t and t+1 compute)
        if (tap < 25) {
#pragma unroll
            for (int icb = 0; icb < 3; ++icb) {
                wq2[icb] = *(const s16x8*)(wqlane + (tap + 2) * (CC * CC) + icb * 32);
                wk2[icb] = *(const s16x8*)(wklane + (tap + 2) * (CC * CC) + icb * 32);
            }
        }
        const int kd = tap / 9, kh = (tap / 3) % 3, kw = tap % 3;
        const int hh = hj + kh - 1, ww = wj + kw - 1;
        const bool valid = ((unsigned)hh < 4u) && ((unsigned)ww < 4u);
        const int rA = valid ? (kd * 16 + hh * 4 + ww) : 64;       // slice t=0
        const int rB = valid ? ((1 + kd) * 16 + hh * 4 + ww) : 64; // slice t=1
        const short* xrA = &xs[rA * 104 + 8 * g];
        const short* xrB = &xs[rB * 104 + 8 * g];
#pragma unroll
        for (int icb = 0; icb < 3; ++icb) {
            s16x8 afA = *(const s16x8*)(xrA + icb * 32);
            s16x8 afB = *(const s16x8*)(xrB + icb * 32);
            accQA = MFMA16(afA, wq0[icb], accQA);
            accQB = MFMA16(afB, wq0[icb], accQB);
            accKA = MFMA16(afA, wk0[icb], accKA);
            accKB = MFMA16(afB, wk0[icb], accKB);
            if (tap == 13) {   // V rides the center tap's A-frags
                s16x8 bv = *(const s16x8*)(wvlane + icb * 32);
                avA = MFMA16(afA, bv, avA);
                avB = MFMA16(afB, bv, avB);
            }
        }
        // rotate ring (register renames under full unroll)
        if (tap < 26) {
#pragma unroll
            for (int icb = 0; icb < 3; ++icb) {
                wq0[icb] = wq1[icb];
                wk0[icb] = wk1[icb];
                wq1[icb] = wq2[icb];
                wk1[icb] = wk2[icb];
            }
        }
    }

    // epilogue
    const float qs = 1.4426950408889634f / sgp[0];
    const int oc = oc0 + j, h = oc / HD, hd = oc % HD;
    const float bq_ = bias_q[oc], bk_ = bias_k[oc];
    const size_t headbase = (size_t)(b * NHH + h) * NN;
    short* QpA = Qb + (headbase + (d0 + 0) * 16 + 4 * g) * 32 + hd;
    short* QpB = Qb + (headbase + (d0 + 1) * 16 + 4 * g) * 32 + hd;
    short* KpA = Kb + (headbase + (d0 + 0) * 16 + 4 * g) * 32 + hd;
    short* KpB = Kb + (headbase + (d0 + 1) * 16 + 4 * g) * 32 + hd;
#pragma unroll
    for (int r = 0; r < 4; ++r) {
        QpA[r * 32] = f2bf((accQA[r] + bq_) * qs);
        QpB[r * 32] = f2bf((accQB[r] + bq_) * qs);
        KpA[r * 32] = f2bf(accKA[r] + bk_);
        KpB[r * 32] = f2bf(accKB[r] + bk_);
    }
    {
        short* Vb = Vtp + (size_t)(b * NHH + h) * (NN * 32);
        const int dh = hd >> 4, dj = hd & 15;
#pragma unroll
        for (int r = 0; r < 4; ++r) {
            int nA = d0 * 16 + 4 * g + r;
            int nB = nA + 16;
            int wA = vslot(nA & 63), wB = vslot(nB & 63);
            Vb[(nA >> 6) * 2048 + ((wA >> 5) * 2 + dh) * 512 + dj * 32 + (wA & 31)] = f2bf(avA[r]);
            Vb[(nB >> 6) * 2048 + ((wB >> 5) * 2 + dh) * 512 + dj * 32 + (wB & 31)] = f2bf(avB[r]);
        }
    }
    if (z == 0 && w == 0) {
        const int n = (d0 + ((l >> 4) & 1)) * 16 + (l & 15);
        const s16x8 z8 = {0, 0, 0, 0, 0, 0, 0, 0};
#pragma unroll
        for (int it = 0; it < 2; ++it) {
            int h2 = (l >> 5) + 2 * it;
            *(s16x8*)(Qb + ((size_t)(b * NHH + h2) * NN + n) * 32 + 24) = z8;
            *(s16x8*)(Kb + ((size_t)(b * NHH + h2) * NN + n) * 32 + 24) = z8;
        }
        const int wN = vslot(n & 63);
#pragma unroll
        for (int it2 = 0; it2 < 2; ++it2) {
            int h3 = it2 * 2 + (l >> 5);
            short* pb = Vtp + (size_t)(b * NHH + h3) * (NN * 32)
                      + (n >> 6) * 2048 + ((wN >> 5) * 2 + 1) * 512 + (wN & 31);
#pragma unroll
            for (int dj = 8; dj < 16; ++dj)
                pb[dj * 32] = 0;
        }
    }
}

// MFMA flash attention — r10 (proven, byte-identical).
#define SOFTTILE(S0, S1, S2, S3, MX, LP, OA, OB, P0, P1) {                      \
    float v0 = fmaxf(fmaxf(S0[0], S0[1]), fmaxf(S0[2], S0[3]));                 \
    float v1 = fmaxf(fmaxf(S1[0], S1[1]), fmaxf(S1[2], S1[3]));                 \
    float v2 = fmaxf(fmaxf(S2[0], S2[1]), fmaxf(S2[2], S2[3]));                 \
    float v3 = fmaxf(fmaxf(S3[0], S3[1]), fmaxf(S3[2], S3[3]));                 \
    float vmx = fmaxf(fmaxf(v0, v1), fmaxf(v2, v3));                            \
    vmx = fmaxf(vmx, __shfl_xor(vmx, 16));                                      \
    vmx = fmaxf(vmx, __shfl_xor(vmx, 32));                                      \
    float nm = fmaxf(MX, vmx);                                                  \
    float sc = EXP2(MX - nm);                                                   \
    MX = nm;                                                                    \
    LP *= sc; OA *= sc; OB *= sc;                                               \
    float p00 = EXP2(S0[0] - MX), p01 = EXP2(S0[1] - MX);                       \
    float p02 = EXP2(S0[2] - MX), p03 = EXP2(S0[3] - MX);                       \
    float p10 = EXP2(S1[0] - MX), p11 = EXP2(S1[1] - MX);                       \
    float p12 = EXP2(S1[2] - MX), p13 = EXP2(S1[3] - MX);                       \
    float p20 = EXP2(S2[0] - MX), p21 = EXP2(S2[1] - MX);                       \
    float p22 = EXP2(S2[2] - MX), p23 = EXP2(S2[3] - MX);                       \
    float p30 = EXP2(S3[0] - MX), p31 = EXP2(S3[1] - MX);                       \
    float p32 = EXP2(S3[2] - MX), p33 = EXP2(S3[3] - MX);                       \
    LP += (((p00 + p01) + (p02 + p03)) + ((p10 + p11) + (p12 + p13)))           \
        + (((p20 + p21) + (p22 + p23)) + ((p30 + p31) + (p32 + p33)));          \
    u32x4 w0_ = { bf16pk(p00, p01), bf16pk(p02, p03),                           \
                  bf16pk(p10, p11), bf16pk(p12, p13) };                         \
    u32x4 w1_ = { bf16pk(p20, p21), bf16pk(p22, p23),                           \
                  bf16pk(p30, p31), bf16pk(p32, p33) };                         \
    P0 = __builtin_bit_cast(s16x8, w0_);                                        \
    P1 = __builtin_bit_cast(s16x8, w1_);                                        \
}

__global__ __launch_bounds__(256) void attn_kernel(
        const short* __restrict__ Qb, const short* __restrict__ Kb,
        const short* __restrict__ Vtp, float* __restrict__ att) {
    __shared__ __align__(16) float comb[3][64][20];
    const int bh = blockIdx.x & 15;            // pins bh pairs per XCD for L2 reuse
    const int q0 = (blockIdx.x >> 4) * 32;
    const int b = bh >> 2, h = bh & 3;
    const int tid = threadIdx.x, wvid = tid >> 6, l = tid & 63;
    const int j = l & 15, g = l >> 4;

    const s16x8 qf0 = *(const s16x8*)(Qb + ((size_t)bh * NN + q0 + j) * 32 + 8 * g);
    const s16x8 qf1 = *(const s16x8*)(Qb + ((size_t)bh * NN + q0 + 16 + j) * 32 + 8 * g);
    const short* Kbase = Kb  + (size_t)bh * NN * 32 + (size_t)j * 32 + 8 * g;
    const short* Vbase = Vtp + (size_t)bh * NN * 32 + (size_t)j * 32 + 8 * g;

    f32x4 oA0 = {0,0,0,0}, oB0 = {0,0,0,0};    // q-tile 0: O^T dims 4g.. / 16+4g..
    f32x4 oA1 = {0,0,0,0}, oB1 = {0,0,0,0};    // q-tile 1
    float mx0 = -1e30f, lp0 = 0.f, mx1 = -1e30f, lp1 = 0.f;
    const f32x4 z = {0,0,0,0};

    const int tbeg = wvid * (NN / 4);
    const int tend = tbeg + NN / 4;            // 640 keys, 10 tiles per wave

    for (int t0 = tbeg; t0 < tend; t0 += 64) {
        const short* kp = Kbase + (size_t)t0 * 32;
        s16x8 k0 = *(const s16x8*)(kp);
        s16x8 k1 = *(const s16x8*)(kp + 512);
        s16x8 k2 = *(const s16x8*)(kp + 1024);
        s16x8 k3 = *(const s16x8*)(kp + 1536);
        const short* vp = Vbase + (size_t)t0 * 32;     // tile base: t0/64*2048
        s16x8 vA0 = *(const s16x8*)(vp);               // (s0,d0)
        s16x8 vB0 = *(const s16x8*)(vp + 512);         // (s0,d1)
        s16x8 vA1 = *(const s16x8*)(vp + 1024);        // (s1,d0)
        s16x8 vB1 = *(const s16x8*)(vp + 1536);        // (s1,d1)

        f32x4 s0 = __builtin_amdgcn_mfma_f32_16x16x32_bf16(k0, qf0, z, 0, 0, 0);
        f32x4 s1 = __builtin_amdgcn_mfma_f32_16x16x32_bf16(k1, qf0, z, 0, 0, 0);
        f32x4 s2 = __builtin_amdgcn_mfma_f32_16x16x32_bf16(k2, qf0, z, 0, 0, 0);
        f32x4 s3 = __builtin_amdgcn_mfma_f32_16x16x32_bf16(k3, qf0, z, 0, 0, 0);
        s16x8 P00, P01;
        SOFTTILE(s0, s1, s2, s3, mx0, lp0, oA0, oB0, P00, P01)

        f32x4 t0s = __builtin_amdgcn_mfma_f32_16x16x32_bf16(k0, qf1, z, 0, 0, 0);
        f32x4 t1s = __builtin_amdgcn_mfma_f32_16x16x32_bf16(k1, qf1, z, 0, 0, 0);
        f32x4 t2s = __builtin_amdgcn_mfma_f32_16x16x32_bf16(k2, qf1, z, 0, 0, 0);
        f32x4 t3s = __builtin_amdgcn_mfma_f32_16x16x32_bf16(k3, qf1, z, 0, 0, 0);
        s16x8 P10, P11;
        SOFTTILE(t0s, t1s, t2s, t3s, mx1, lp1, oA1, oB1, P10, P11)

        oA0 = __builtin_amdgcn_mfma_f32_16x16x32_bf16(vA0, P00, oA0, 0, 0, 0);
        oA0 = __builtin_amdgcn_mfma_f32_16x16x32_bf16(vA1, P01, oA0, 0, 0, 0);
        oB0 = __builtin_amdgcn_mfma_f32_16x16x32_bf16(vB0, P00, oB0, 0, 0, 0);
        oB0 = __builtin_amdgcn_mfma_f32_16x16x32_bf16(vB1, P01, oB0, 0, 0, 0);
        oA1 = __builtin_amdgcn_mfma_f32_16x16x32_bf16(vA0, P10, oA1, 0, 0, 0);
        oA1 = __builtin_amdgcn_mfma_f32_16x16x32_bf16(vA1, P11, oA1, 0, 0, 0);
        oB1 = __builtin_amdgcn_mfma_f32_16x16x32_bf16(vB0, P10, oB1, 0, 0, 0);
        oB1 = __builtin_amdgcn_mfma_f32_16x16x32_bf16(vB1, P11, oB1, 0, 0, 0);
    }

    // row-sum lp across the 4 g-lanes
    lp0 += __shfl_xor(lp0, 16); lp0 += __shfl_xor(lp0, 32);
    lp1 += __shfl_xor(lp1, 16); lp1 += __shfl_xor(lp1, 32);

    if (wvid != 0) {
        float* cp = comb[wvid - 1][l];
        cp[0] = mx0; cp[1] = lp0; cp[2] = mx1; cp[3] = lp1;
        *(f32x4*)(cp + 4)  = oA0;
        *(f32x4*)(cp + 8)  = oB0;
        *(f32x4*)(cp + 12) = oA1;
        *(f32x4*)(cp + 16) = oB1;
    }
    __syncthreads();
    if (wvid != 0) return;

#pragma unroll
    for (int wv = 0; wv < 3; ++wv) {
        const float* cp = comb[wv][l];
        {
            float mb = cp[0], lb = cp[1];
            f32x4 oAb = *(const f32x4*)(cp + 4);
            f32x4 oBb = *(const f32x4*)(cp + 8);
            float mm = fmaxf(mx0, mb);
            float sa = EXP2(mx0 - mm), sb = EXP2(mb - mm);
            mx0 = mm;
            lp0 = lp0 * sa + lb * sb;
            oA0 = oA0 * sa + oAb * sb;
            oB0 = oB0 * sa + oBb * sb;
        }
        {
            float mb = cp[2], lb = cp[3];
            f32x4 oAb = *(const f32x4*)(cp + 12);
            f32x4 oBb = *(const f32x4*)(cp + 16);
            float mm = fmaxf(mx1, mb);
            float sa = EXP2(mx1 - mm), sb = EXP2(mb - mm);
            mx1 = mm;
            lp1 = lp1 * sa + lb * sb;
            oA1 = oA1 * sa + oAb * sb;
            oB1 = oB1 * sa + oBb * sb;
        }
    }

    const float rl0 = 1.f / lp0, rl1 = 1.f / lp1;
    f32x4 rA0 = oA0 * rl0, rB0 = oB0 * rl0;
    f32x4 rA1 = oA1 * rl1, rB1 = oB1 * rl1;

    float* op0 = att + ((size_t)b * NN + q0 + j) * CC + h * HD;
    float* op1 = att + ((size_t)b * NN + q0 + 16 + j) * CC + h * HD;
    *(f32x4*)(op0 + 4 * g) = rA0;
    *(f32x4*)(op1 + 4 * g) = rA1;
    if (g < 2) {
        *(f32x4*)(op0 + 16 + 4 * g) = rB0;
        *(f32x4*)(op1 + 16 + 4 * g) = rB1;
    }
}

// MFMA out-projection — r16 (proven, byte-identical).
__global__ __launch_bounds__(256) void proj_kernel(
        const float* __restrict__ att, const short* __restrict__ wo_b,
        const float* __restrict__ bo, float* __restrict__ out) {
    __shared__ __align__(16) short als[64 * 104];
    const int t0 = blockIdx.x * 64;
    const int tid = threadIdx.x;
#pragma unroll
    for (int k = 0; k < 6; ++k) {
        int c = tid + k * 256;                      // 1536 chunks
        int row = c / 24, ic0 = (c % 24) * 4;
        f32x4 v = *(const f32x4*)(att + (size_t)(t0 + row) * CC + ic0);
        u32x2 o = { bf16pk(v[0], v[1]), bf16pk(v[2], v[3]) };
        *(u32x2*)&als[row * 104 + ic0] = o;
    }
    __syncthreads();

    const int w = tid >> 6, l = tid & 63;
    const int j = l & 15, g = l >> 4;
    const short* ap = &als[(w * 16 + j) * 104 + 8 * g];
    s16x8 a0 = *(const s16x8*)(ap);
    s16x8 a1 = *(const s16x8*)(ap + 32);
    s16x8 a2 = *(const s16x8*)(ap + 64);
    const f32x4 zz = {0, 0, 0, 0};
    float* ob = out + (size_t)(t0 + w * 16 + 4 * g) * CC + j;
#pragma unroll
    for (int oct = 0; oct < 6; ++oct) {
        const short* wp = wo_b + oct * 3 * 512 + j * 32 + 8 * g;
        f32x4 acc = zz;
        acc = __builtin_amdgcn_mfma_f32_16x16x32_bf16(a0, *(const s16x8*)(wp),        acc, 0, 0, 0);
        acc = __builtin_amdgcn_mfma_f32_16x16x32_bf16(a1, *(const s16x8*)(wp + 512),  acc, 0, 0, 0);
        acc = __builtin_amdgcn_mfma_f32_16x16x32_bf16(a2, *(const s16x8*)(wp + 1024), acc, 0, 0, 0);
        const float bb = bo[oct * 16 + j];
#pragma unroll
        for (int r = 0; r < 4; ++r)
            ob[(size_t)r * CC + oct * 16] = acc[r] + bb;
    }
}

extern "C" void kernel_launch(void* const* d_in, const int* in_sizes, int n_in,
                              void* d_out, int out_size, void* d_ws, size_t ws_size,
                              hipStream_t stream) {
    const float* x     = (const float*)d_in[0];
    const float* sg    = (const float*)d_in[1];
    const float* wq    = (const float*)d_in[2];
    const float* bnq_g = (const float*)d_in[3];
    const float* bnq_b = (const float*)d_in[4];
    const float* bnq_m = (const float*)d_in[5];
    const float* bnq_v = (const float*)d_in[6];
    const float* wk    = (const float*)d_in[7];
    const float* bnk_g = (const float*)d_in[8];
    const float* bnk_b = (const float*)d_in[9];
    const float* bnk_m = (const float*)d_in[10];
    const float* bnk_v = (const float*)d_in[11];
    const float* wv    = (const float*)d_in[12];
    const float* wo    = (const float*)d_in[13];
    const float* bo    = (const float*)d_in[14];

    float* ws = (float*)d_ws;
    short* wq_b   = (short*)(ws + WS_WQ);
    short* wk_b   = (short*)(ws + WS_WK);
    short* wv_b   = (short*)(ws + WS_WV);
    float* bias_q = ws + WS_BQ;
    float* bias_k = ws + WS_BK;
    float* attw   = ws + WS_ATT;
    short* Qb     = (short*)(ws + WS_QB);
    short* Kb     = (short*)(ws + WS_KB);
    short* Vtp    = (short*)(ws + WS_VT);
    short* wo_b   = (short*)(ws + WS_WO);

    prep_w<<<dim3(CC), dim3(128), 0, stream>>>(wq, bnq_g, bnq_b, bnq_m, bnq_v, wq_b, bias_q,
                                               wv, wv_b);
    prep_w<<<dim3(CC), dim3(128), 0, stream>>>(wk, bnk_g, bnk_b, bnk_m, bnk_v, wk_b, bias_k,
                                               nullptr, nullptr);
    prep_wo<<<dim3(36), dim3(256), 0, stream>>>(wo, wo_b);

    qkv_conv<<<dim3(DEPTH / 2, BB, 2), dim3(192), 0, stream>>>(
        x, wq_b, wk_b, wv_b, bias_q, bias_k, sg, Qb, Kb, Vtp);

    attn_kernel<<<dim3(NN / 32 * 16), dim3(256), 0, stream>>>(Qb, Kb, Vtp, attw);

    proj_kernel<<<dim3(BB * NN / 64), dim3(256), 0, stream>>>(attw, wo_b, bo, (float*)d_out);
}

// Round 20
// 74.847 us; speedup vs baseline: 1.2532x; 1.0458x over previous
//
#include <hip/hip_runtime.h>
#include <hip/hip_bf16.h>

#define BB 4
#define DEPTH 160
#define CC 96
#define NN 2560          // DEPTH*16
#define NHH 4
#define HD 24
#define THETA 0.6f
#define BN_EPS 1e-5f

typedef __attribute__((ext_vector_type(4))) float f32x4;
typedef __attribute__((ext_vector_type(8))) short s16x8;
typedef __attribute__((ext_vector_type(4))) short s16x4;
typedef __attribute__((ext_vector_type(2))) unsigned u32x2;
typedef __attribute__((ext_vector_type(4))) unsigned u32x4;

#if __has_builtin(__builtin_amdgcn_exp2f)
#define EXP2(x) __builtin_amdgcn_exp2f(x)
#else
#define EXP2(x) exp2f(x)
#endif

// ---------------------------------------------------------------------------
// Workspace layout (float slots):
//   wq_b  : bf16 [tap][oc][ic] 27*96*96 shorts  -> 124416 slots (r10 layout)
//   wk_b  : 124416
//   wv_b  : bf16 [oc][ic] 9216 shorts -> 4608
//   bias_q: 96, bias_k: 96 (fp32)
//   att   : fp32 [b][n][96]                     -> 983040
//   Qb    : bf16 [bh][n][32] (hd 24..31 zeroed) -> 655360
//   Kb    : bf16 [bh][n][32]                    -> 655360
//   Vtp   : bf16 [bh][tile][s*2+dh][16 dims][32 slots] — per-64-key-tile blocked
//   wo_b  : bf16 frag-blocked [oct 6][icb 3][j16 x 32ic] -> 4608 slots
// ---------------------------------------------------------------------------
#define WS_WQ   0
#define WS_WK   124416
#define WS_WV   248832
#define WS_BQ   253440
#define WS_BK   253536
#define WS_ATT  253632
#define WS_QB   1236672
#define WS_KB   1892032
#define WS_VT   2547392
#define WS_WO   3202752

__device__ __forceinline__ short f2bf(float f) {
    unsigned u = __float_as_uint(f);
    u += 0x7fffu + ((u >> 16) & 1u);
    return (short)(u >> 16);
}
__device__ __forceinline__ unsigned bf16pk(float lo, float hi) {
    unsigned r;
    asm("v_cvt_pk_bf16_f32 %0, %1, %2" : "=v"(r) : "v"(lo), "v"(hi));
    return r;
}
// PV slot of key n within its 64-token tile (bit5 = s-half kept, low 5 permuted
// so the P B-fragment is the lane's own QK^T output).
__device__ __forceinline__ int vslot(int n) {
    return (n & 32) | (((n >> 2) & 3) << 3) | (((n >> 4) & 1) << 2) | (n & 3);
}

// FUSED prep: one launch does all weight preprocessing (was 3 serialized
// launches of tiny latency-bound grids).
//   blockIdx.y == 0: Q conv weights (TCDC+BN fold) + V 1x1x1 weights
//   blockIdx.y == 1: K conv weights
//   blockIdx.y == 2: wo -> fragment-blocked bf16
__global__ void prep_all(
        const float* __restrict__ wq, const float* __restrict__ bnq_g,
        const float* __restrict__ bnq_b, const float* __restrict__ bnq_m,
        const float* __restrict__ bnq_v,
        const float* __restrict__ wk, const float* __restrict__ bnk_g,
        const float* __restrict__ bnk_b, const float* __restrict__ bnk_m,
        const float* __restrict__ bnk_v,
        const float* __restrict__ wv, const float* __restrict__ wo,
        short* __restrict__ wq_b, short* __restrict__ wk_b,
        short* __restrict__ wv_b, short* __restrict__ wo_b,
        float* __restrict__ bias_q, float* __restrict__ bias_k) {
    const int y = blockIdx.y;
    if (y == 2) {
        int i = blockIdx.x * 128 + threadIdx.x;     // 96*128 = 12288 >= 9216
        if (i < CC * CC) {
            int oc = i / CC, ic = i % CC;
            wo_b[(((oc >> 4) * 3 + (ic >> 5)) << 9) + (oc & 15) * 32 + (ic & 31)] =
                f2bf(wo[i]);
        }
        return;
    }
    const float* w     = y ? wk    : wq;
    const float* gamma = y ? bnk_g : bnq_g;
    const float* beta  = y ? bnk_b : bnq_b;
    const float* mean  = y ? bnk_m : bnq_m;
    const float* var   = y ? bnk_v : bnq_v;
    short* w_eff = y ? wk_b : wq_b;
    float* bias  = y ? bias_k : bias_q;

    int oc = blockIdx.x;
    int ic = threadIdx.x;
    if (ic >= CC) return;
    float scale = gamma[oc] * rsqrtf(var[oc] + BN_EPS);
    if (ic == 0) bias[oc] = beta[oc] - mean[oc] * scale;
    const float* wp = w + (oc * CC + ic) * 27;
    float kdiff = 0.f;
#pragma unroll
    for (int t = 0; t < 9; ++t) kdiff += wp[t] + wp[18 + t];
#pragma unroll
    for (int t = 0; t < 27; ++t) {
        float v = wp[t];
        if (t == 13) v -= THETA * kdiff;     // center tap (1,1,1)
        w_eff[t * (CC * CC) + oc * CC + ic] = f2bf(v * scale);
    }
    if (y == 0) wv_b[oc * CC + ic] = f2bf(wv[oc * CC + ic]);
}

#define MFMA16(A, B, C) __builtin_amdgcn_mfma_f32_16x16x32_bf16(A, B, C, 0, 0, 0)

// MFMA im2col conv — r19 (proven-best, byte-identical): 2-tap-deep register
// weight pipeline; block = (2 depth slices) x (oc-half); 3 waves = oct(3).
__global__ __launch_bounds__(192) void qkv_conv(
        const float* __restrict__ x, const short* __restrict__ wq_b,
        const short* __restrict__ wk_b, const short* __restrict__ wv_b,
        const float* __restrict__ bias_q, const float* __restrict__ bias_k,
        const float* __restrict__ sgp,
        short* __restrict__ Qb, short* __restrict__ Kb, short* __restrict__ Vtp) {
    __shared__ __align__(16) short xs[65 * 104];   // 64 rows + zero row, stride 104
    const int b = blockIdx.y;
    const int d0 = blockIdx.x * 2;
    const int z = blockIdx.z;                       // oc-half
    const int tid = threadIdx.x;

    // stage 4 slices (d0-1 .. d0+2), f32 -> bf16 via cvt_pk; 1536 chunks
#pragma unroll
    for (int k = 0; k < 8; ++k) {
        int c = tid + k * 192;
        int row = c / 24, ic0 = (c % 24) * 4;
        int dg = d0 - 1 + (row >> 4), pos = row & 15;
        u32x2 o = {0u, 0u};
        if (dg >= 0 && dg < DEPTH) {
            f32x4 v = *(const f32x4*)(x + ((size_t)(b * NN + dg * 16 + pos)) * CC + ic0);
            o[0] = bf16pk(v[0], v[1]);
            o[1] = bf16pk(v[2], v[3]);
        }
        *(u32x2*)&xs[row * 104 + ic0] = o;
    }
    if (tid < 26) *(u32x2*)&xs[64 * 104 + tid * 4] = (u32x2){0u, 0u};
    __syncthreads();

    const int w  = tid >> 6, l = tid & 63;          // w = oct
    const int j  = l & 15, g = l >> 4;
    const int oc0 = z * 48 + w * 16;
    const int hj = j >> 2, wj = j & 3;

    const short* wqlane = wq_b + (oc0 + j) * CC + 8 * g;
    const short* wklane = wk_b + (oc0 + j) * CC + 8 * g;
    const short* wvlane = wv_b + (oc0 + j) * CC + 8 * g;

    f32x4 accQA = {0,0,0,0}, accQB = {0,0,0,0};
    f32x4 accKA = {0,0,0,0}, accKB = {0,0,0,0};
    f32x4 avA   = {0,0,0,0}, avB   = {0,0,0,0};

    // 3-slot register ring: taps t (compute), t+1, t+2 (in flight)
    s16x8 wq0[3], wk0[3], wq1[3], wk1[3], wq2[3], wk2[3];
#pragma unroll
    for (int icb = 0; icb < 3; ++icb) {
        wq0[icb] = *(const s16x8*)(wqlane + 0 * (CC * CC) + icb * 32);
        wk0[icb] = *(const s16x8*)(wklane + 0 * (CC * CC) + icb * 32);
        wq1[icb] = *(const s16x8*)(wqlane + 1 * (CC * CC) + icb * 32);
        wk1[icb] = *(const s16x8*)(wklane + 1 * (CC * CC) + icb * 32);
    }

#pragma unroll
    for (int tap = 0; tap < 27; ++tap) {
        if (tap < 25) {
#pragma unroll
            for (int icb = 0; icb < 3; ++icb) {
                wq2[icb] = *(const s16x8*)(wqlane + (tap + 2) * (CC * CC) + icb * 32);
                wk2[icb] = *(const s16x8*)(wklane + (tap + 2) * (CC * CC) + icb * 32);
            }
        }
        const int kd = tap / 9, kh = (tap / 3) % 3, kw = tap % 3;
        const int hh = hj + kh - 1, ww = wj + kw - 1;
        const bool valid = ((unsigned)hh < 4u) && ((unsigned)ww < 4u);
        const int rA = valid ? (kd * 16 + hh * 4 + ww) : 64;       // slice t=0
        const int rB = valid ? ((1 + kd) * 16 + hh * 4 + ww) : 64; // slice t=1
        const short* xrA = &xs[rA * 104 + 8 * g];
        const short* xrB = &xs[rB * 104 + 8 * g];
#pragma unroll
        for (int icb = 0; icb < 3; ++icb) {
            s16x8 afA = *(const s16x8*)(xrA + icb * 32);
            s16x8 afB = *(const s16x8*)(xrB + icb * 32);
            accQA = MFMA16(afA, wq0[icb], accQA);
            accQB = MFMA16(afB, wq0[icb], accQB);
            accKA = MFMA16(afA, wk0[icb], accKA);
            accKB = MFMA16(afB, wk0[icb], accKB);
            if (tap == 13) {   // V rides the center tap's A-frags
                s16x8 bv = *(const s16x8*)(wvlane + icb * 32);
                avA = MFMA16(afA, bv, avA);
                avB = MFMA16(afB, bv, avB);
            }
        }
        if (tap < 26) {
#pragma unroll
            for (int icb = 0; icb < 3; ++icb) {
                wq0[icb] = wq1[icb];
                wk0[icb] = wk1[icb];
                wq1[icb] = wq2[icb];
                wk1[icb] = wk2[icb];
            }
        }
    }

    // epilogue
    const float qs = 1.4426950408889634f / sgp[0];
    const int oc = oc0 + j, h = oc / HD, hd = oc % HD;
    const float bq_ = bias_q[oc], bk_ = bias_k[oc];
    const size_t headbase = (size_t)(b * NHH + h) * NN;
    short* QpA = Qb + (headbase + (d0 + 0) * 16 + 4 * g) * 32 + hd;
    short* QpB = Qb + (headbase + (d0 + 1) * 16 + 4 * g) * 32 + hd;
    short* KpA = Kb + (headbase + (d0 + 0) * 16 + 4 * g) * 32 + hd;
    short* KpB = Kb + (headbase + (d0 + 1) * 16 + 4 * g) * 32 + hd;
#pragma unroll
    for (int r = 0; r < 4; ++r) {
        QpA[r * 32] = f2bf((accQA[r] + bq_) * qs);
        QpB[r * 32] = f2bf((accQB[r] + bq_) * qs);
        KpA[r * 32] = f2bf(accKA[r] + bk_);
        KpB[r * 32] = f2bf(accKB[r] + bk_);
    }
    {
        short* Vb = Vtp + (size_t)(b * NHH + h) * (NN * 32);
        const int dh = hd >> 4, dj = hd & 15;
#pragma unroll
        for (int r = 0; r < 4; ++r) {
            int nA = d0 * 16 + 4 * g + r;
            int nB = nA + 16;
            int wA = vslot(nA & 63), wB = vslot(nB & 63);
            Vb[(nA >> 6) * 2048 + ((wA >> 5) * 2 + dh) * 512 + dj * 32 + (wA & 31)] = f2bf(avA[r]);
            Vb[(nB >> 6) * 2048 + ((wB >> 5) * 2 + dh) * 512 + dj * 32 + (wB & 31)] = f2bf(avB[r]);
        }
    }
    if (z == 0 && w == 0) {
        const int n = (d0 + ((l >> 4) & 1)) * 16 + (l & 15);
        const s16x8 z8 = {0, 0, 0, 0, 0, 0, 0, 0};
#pragma unroll
        for (int it = 0; it < 2; ++it) {
            int h2 = (l >> 5) + 2 * it;
            *(s16x8*)(Qb + ((size_t)(b * NHH + h2) * NN + n) * 32 + 24) = z8;
            *(s16x8*)(Kb + ((size_t)(b * NHH + h2) * NN + n) * 32 + 24) = z8;
        }
        const int wN = vslot(n & 63);
#pragma unroll
        for (int it2 = 0; it2 < 2; ++it2) {
            int h3 = it2 * 2 + (l >> 5);
            short* pb = Vtp + (size_t)(b * NHH + h3) * (NN * 32)
                      + (n >> 6) * 2048 + ((wN >> 5) * 2 + 1) * 512 + (wN & 31);
#pragma unroll
            for (int dj = 8; dj < 16; ++dj)
                pb[dj * 32] = 0;
        }
    }
}

// MFMA flash attention — r10 structure + (a) EXACT skip of the online rescale
// when no row's max grew (wave-uniform __any; sc==1.0 for every lane when
// skipped, so math is bit-identical), (b) 2x unrolled K-tile loop for MLP.
#define SOFTTILE(S0, S1, S2, S3, MX, LP, OA, OB, P0, P1) {                      \
    float v0 = fmaxf(fmaxf(S0[0], S0[1]), fmaxf(S0[2], S0[3]));                 \
    float v1 = fmaxf(fmaxf(S1[0], S1[1]), fmaxf(S1[2], S1[3]));                 \
    float v2 = fmaxf(fmaxf(S2[0], S2[1]), fmaxf(S2[2], S2[3]));                 \
    float v3 = fmaxf(fmaxf(S3[0], S3[1]), fmaxf(S3[2], S3[3]));                 \
    float vmx = fmaxf(fmaxf(v0, v1), fmaxf(v2, v3));                            \
    vmx = fmaxf(vmx, __shfl_xor(vmx, 16));                                      \
    vmx = fmaxf(vmx, __shfl_xor(vmx, 32));                                      \
    if (__any(vmx > MX)) {                                                      \
        float nm = fmaxf(MX, vmx);                                              \
        float sc = EXP2(MX - nm);                                               \
        MX = nm;                                                                \
        LP *= sc; OA *= sc; OB *= sc;                                           \
    }                                                                           \
    float p00 = EXP2(S0[0] - MX), p01 = EXP2(S0[1] - MX);                       \
    float p02 = EXP2(S0[2] - MX), p03 = EXP2(S0[3] - MX);                       \
    float p10 = EXP2(S1[0] - MX), p11 = EXP2(S1[1] - MX);                       \
    float p12 = EXP2(S1[2] - MX), p13 = EXP2(S1[3] - MX);                       \
    float p20 = EXP2(S2[0] - MX), p21 = EXP2(S2[1] - MX);                       \
    float p22 = EXP2(S2[2] - MX), p23 = EXP2(S2[3] - MX);                       \
    float p30 = EXP2(S3[0] - MX), p31 = EXP2(S3[1] - MX);                       \
    float p32 = EXP2(S3[2] - MX), p33 = EXP2(S3[3] - MX);                       \
    LP += (((p00 + p01) + (p02 + p03)) + ((p10 + p11) + (p12 + p13)))           \
        + (((p20 + p21) + (p22 + p23)) + ((p30 + p31) + (p32 + p33)));          \
    u32x4 w0_ = { bf16pk(p00, p01), bf16pk(p02, p03),                           \
                  bf16pk(p10, p11), bf16pk(p12, p13) };                         \
    u32x4 w1_ = { bf16pk(p20, p21), bf16pk(p22, p23),                           \
                  bf16pk(p30, p31), bf16pk(p32, p33) };                         \
    P0 = __builtin_bit_cast(s16x8, w0_);                                        \
    P1 = __builtin_bit_cast(s16x8, w1_);                                        \
}

__global__ __launch_bounds__(256) void attn_kernel(
        const short* __restrict__ Qb, const short* __restrict__ Kb,
        const short* __restrict__ Vtp, float* __restrict__ att) {
    __shared__ __align__(16) float comb[3][64][20];
    const int bh = blockIdx.x & 15;            // pins bh pairs per XCD for L2 reuse
    const int q0 = (blockIdx.x >> 4) * 32;
    const int b = bh >> 2, h = bh & 3;
    const int tid = threadIdx.x, wvid = tid >> 6, l = tid & 63;
    const int j = l & 15, g = l >> 4;

    const s16x8 qf0 = *(const s16x8*)(Qb + ((size_t)bh * NN + q0 + j) * 32 + 8 * g);
    const s16x8 qf1 = *(const s16x8*)(Qb + ((size_t)bh * NN + q0 + 16 + j) * 32 + 8 * g);
    const short* Kbase = Kb  + (size_t)bh * NN * 32 + (size_t)j * 32 + 8 * g;
    const short* Vbase = Vtp + (size_t)bh * NN * 32 + (size_t)j * 32 + 8 * g;

    f32x4 oA0 = {0,0,0,0}, oB0 = {0,0,0,0};    // q-tile 0: O^T dims 4g.. / 16+4g..
    f32x4 oA1 = {0,0,0,0}, oB1 = {0,0,0,0};    // q-tile 1
    float mx0 = -1e30f, lp0 = 0.f, mx1 = -1e30f, lp1 = 0.f;
    const f32x4 z = {0,0,0,0};

    const int tbeg = wvid * (NN / 4);
    const int tend = tbeg + NN / 4;            // 640 keys, 10 tiles per wave

#pragma unroll 2
    for (int t0 = tbeg; t0 < tend; t0 += 64) {
        const short* kp = Kbase + (size_t)t0 * 32;
        s16x8 k0 = *(const s16x8*)(kp);
        s16x8 k1 = *(const s16x8*)(kp + 512);
        s16x8 k2 = *(const s16x8*)(kp + 1024);
        s16x8 k3 = *(const s16x8*)(kp + 1536);
        const short* vp = Vbase + (size_t)t0 * 32;     // tile base: t0/64*2048
        s16x8 vA0 = *(const s16x8*)(vp);               // (s0,d0)
        s16x8 vB0 = *(const s16x8*)(vp + 512);         // (s0,d1)
        s16x8 vA1 = *(const s16x8*)(vp + 1024);        // (s1,d0)
        s16x8 vB1 = *(const s16x8*)(vp + 1536);        // (s1,d1)

        f32x4 s0 = __builtin_amdgcn_mfma_f32_16x16x32_bf16(k0, qf0, z, 0, 0, 0);
        f32x4 s1 = __builtin_amdgcn_mfma_f32_16x16x32_bf16(k1, qf0, z, 0, 0, 0);
        f32x4 s2 = __builtin_amdgcn_mfma_f32_16x16x32_bf16(k2, qf0, z, 0, 0, 0);
        f32x4 s3 = __builtin_amdgcn_mfma_f32_16x16x32_bf16(k3, qf0, z, 0, 0, 0);
        s16x8 P00, P01;
        SOFTTILE(s0, s1, s2, s3, mx0, lp0, oA0, oB0, P00, P01)

        f32x4 t0s = __builtin_amdgcn_mfma_f32_16x16x32_bf16(k0, qf1, z, 0, 0, 0);
        f32x4 t1s = __builtin_amdgcn_mfma_f32_16x16x32_bf16(k1, qf1, z, 0, 0, 0);
        f32x4 t2s = __builtin_amdgcn_mfma_f32_16x16x32_bf16(k2, qf1, z, 0, 0, 0);
        f32x4 t3s = __builtin_amdgcn_mfma_f32_16x16x32_bf16(k3, qf1, z, 0, 0, 0);
        s16x8 P10, P11;
        SOFTTILE(t0s, t1s, t2s, t3s, mx1, lp1, oA1, oB1, P10, P11)

        oA0 = __builtin_amdgcn_mfma_f32_16x16x32_bf16(vA0, P00, oA0, 0, 0, 0);
        oA0 = __builtin_amdgcn_mfma_f32_16x16x32_bf16(vA1, P01, oA0, 0, 0, 0);
        oB0 = __builtin_amdgcn_mfma_f32_16x16x32_bf16(vB0, P00, oB0, 0, 0, 0);
        oB0 = __builtin_amdgcn_mfma_f32_16x16x32_bf16(vB1, P01, oB0, 0, 0, 0);
        oA1 = __builtin_amdgcn_mfma_f32_16x16x32_bf16(vA0, P10, oA1, 0, 0, 0);
        oA1 = __builtin_amdgcn_mfma_f32_16x16x32_bf16(vA1, P11, oA1, 0, 0, 0);
        oB1 = __builtin_amdgcn_mfma_f32_16x16x32_bf16(vB0, P10, oB1, 0, 0, 0);
        oB1 = __builtin_amdgcn_mfma_f32_16x16x32_bf16(vB1, P11, oB1, 0, 0, 0);
    }

    // row-sum lp across the 4 g-lanes
    lp0 += __shfl_xor(lp0, 16); lp0 += __shfl_xor(lp0, 32);
    lp1 += __shfl_xor(lp1, 16); lp1 += __shfl_xor(lp1, 32);

    if (wvid != 0) {
        float* cp = comb[wvid - 1][l];
        cp[0] = mx0; cp[1] = lp0; cp[2] = mx1; cp[3] = lp1;
        *(f32x4*)(cp + 4)  = oA0;
        *(f32x4*)(cp + 8)  = oB0;
        *(f32x4*)(cp + 12) = oA1;
        *(f32x4*)(cp + 16) = oB1;
    }
    __syncthreads();
    if (wvid != 0) return;

#pragma unroll
    for (int wv = 0; wv < 3; ++wv) {
        const float* cp = comb[wv][l];
        {
            float mb = cp[0], lb = cp[1];
            f32x4 oAb = *(const f32x4*)(cp + 4);
            f32x4 oBb = *(const f32x4*)(cp + 8);
            float mm = fmaxf(mx0, mb);
            float sa = EXP2(mx0 - mm), sb = EXP2(mb - mm);
            mx0 = mm;
            lp0 = lp0 * sa + lb * sb;
            oA0 = oA0 * sa + oAb * sb;
            oB0 = oB0 * sa + oBb * sb;
        }
        {
            float mb = cp[2], lb = cp[3];
            f32x4 oAb = *(const f32x4*)(cp + 12);
            f32x4 oBb = *(const f32x4*)(cp + 16);
            float mm = fmaxf(mx1, mb);
            float sa = EXP2(mx1 - mm), sb = EXP2(mb - mm);
            mx1 = mm;
            lp1 = lp1 * sa + lb * sb;
            oA1 = oA1 * sa + oAb * sb;
            oB1 = oB1 * sa + oBb * sb;
        }
    }

    const float rl0 = 1.f / lp0, rl1 = 1.f / lp1;
    f32x4 rA0 = oA0 * rl0, rB0 = oB0 * rl0;
    f32x4 rA1 = oA1 * rl1, rB1 = oB1 * rl1;

    float* op0 = att + ((size_t)b * NN + q0 + j) * CC + h * HD;
    float* op1 = att + ((size_t)b * NN + q0 + 16 + j) * CC + h * HD;
    *(f32x4*)(op0 + 4 * g) = rA0;
    *(f32x4*)(op1 + 4 * g) = rA1;
    if (g < 2) {
        *(f32x4*)(op0 + 16 + 4 * g) = rB0;
        *(f32x4*)(op1 + 16 + 4 * g) = rB1;
    }
}

// MFMA out-projection — r16 (proven, byte-identical).
__global__ __launch_bounds__(256) void proj_kernel(
        const float* __restrict__ att, const short* __restrict__ wo_b,
        const float* __restrict__ bo, float* __restrict__ out) {
    __shared__ __align__(16) short als[64 * 104];
    const int t0 = blockIdx.x * 64;
    const int tid = threadIdx.x;
#pragma unroll
    for (int k = 0; k < 6; ++k) {
        int c = tid + k * 256;                      // 1536 chunks
        int row = c / 24, ic0 = (c % 24) * 4;
        f32x4 v = *(const f32x4*)(att + (size_t)(t0 + row) * CC + ic0);
        u32x2 o = { bf16pk(v[0], v[1]), bf16pk(v[2], v[3]) };
        *(u32x2*)&als[row * 104 + ic0] = o;
    }
    __syncthreads();

    const int w = tid >> 6, l = tid & 63;
    const int j = l & 15, g = l >> 4;
    const short* ap = &als[(w * 16 + j) * 104 + 8 * g];
    s16x8 a0 = *(const s16x8*)(ap);
    s16x8 a1 = *(const s16x8*)(ap + 32);
    s16x8 a2 = *(const s16x8*)(ap + 64);
    const f32x4 zz = {0, 0, 0, 0};
    float* ob = out + (size_t)(t0 + w * 16 + 4 * g) * CC + j;
#pragma unroll
    for (int oct = 0; oct < 6; ++oct) {
        const short* wp = wo_b + oct * 3 * 512 + j * 32 + 8 * g;
        f32x4 acc = zz;
        acc = __builtin_amdgcn_mfma_f32_16x16x32_bf16(a0, *(const s16x8*)(wp),        acc, 0, 0, 0);
        acc = __builtin_amdgcn_mfma_f32_16x16x32_bf16(a1, *(const s16x8*)(wp + 512),  acc, 0, 0, 0);
        acc = __builtin_amdgcn_mfma_f32_16x16x32_bf16(a2, *(const s16x8*)(wp + 1024), acc, 0, 0, 0);
        const float bb = bo[oct * 16 + j];
#pragma unroll
        for (int r = 0; r < 4; ++r)
            ob[(size_t)r * CC + oct * 16] = acc[r] + bb;
    }
}

extern "C" void kernel_launch(void* const* d_in, const int* in_sizes, int n_in,
                              void* d_out, int out_size, void* d_ws, size_t ws_size,
                              hipStream_t stream) {
    const float* x     = (const float*)d_in[0];
    const float* sg    = (const float*)d_in[1];
    const float* wq    = (const float*)d_in[2];
    const float* bnq_g = (const float*)d_in[3];
    const float* bnq_b = (const float*)d_in[4];
    const float* bnq_m = (const float*)d_in[5];
    const float* bnq_v = (const float*)d_in[6];
    const float* wk    = (const float*)d_in[7];
    const float* bnk_g = (const float*)d_in[8];
    const float* bnk_b = (const float*)d_in[9];
    const float* bnk_m = (const float*)d_in[10];
    const float* bnk_v = (const float*)d_in[11];
    const float* wv    = (const float*)d_in[12];
    const float* wo    = (const float*)d_in[13];
    const float* bo    = (const float*)d_in[14];

    float* ws = (float*)d_ws;
    short* wq_b   = (short*)(ws + WS_WQ);
    short* wk_b   = (short*)(ws + WS_WK);
    short* wv_b   = (short*)(ws + WS_WV);
    float* bias_q = ws + WS_BQ;
    float* bias_k = ws + WS_BK;
    float* attw   = ws + WS_ATT;
    short* Qb     = (short*)(ws + WS_QB);
    short* Kb     = (short*)(ws + WS_KB);
    short* Vtp    = (short*)(ws + WS_VT);
    short* wo_b   = (short*)(ws + WS_WO);

    prep_all<<<dim3(CC, 3), dim3(128), 0, stream>>>(
        wq, bnq_g, bnq_b, bnq_m, bnq_v,
        wk, bnk_g, bnk_b, bnk_m, bnk_v,
        wv, wo, wq_b, wk_b, wv_b, wo_b, bias_q, bias_k);

    qkv_conv<<<dim3(DEPTH / 2, BB, 2), dim3(192), 0, stream>>>(
        x, wq_b, wk_b, wv_b, bias_q, bias_k, sg, Qb, Kb, Vtp);

    attn_kernel<<<dim3(NN / 32 * 16), dim3(256), 0, stream>>>(Qb, Kb, Vtp, attw);

    proj_kernel<<<dim3(BB * NN / 64), dim3(256), 0, stream>>>(attw, wo_b, bo, (float*)d_out);
}

// Round 21
// 73.666 us; speedup vs baseline: 1.2733x; 1.0160x over previous
//
#include <hip/hip_runtime.h>
#include <hip/hip_bf16.h>

#define BB 4
#define DEPTH 160
#define CC 96
#define NN 2560          // DEPTH*16
#define NHH 4
#define HD 24
#define THETA 0.6f
#define BN_EPS 1e-5f

typedef __attribute__((ext_vector_type(4))) float f32x4;
typedef __attribute__((ext_vector_type(8))) short s16x8;
typedef __attribute__((ext_vector_type(4))) short s16x4;
typedef __attribute__((ext_vector_type(2))) unsigned u32x2;
typedef __attribute__((ext_vector_type(4))) unsigned u32x4;

#if __has_builtin(__builtin_amdgcn_exp2f)
#define EXP2(x) __builtin_amdgcn_exp2f(x)
#else
#define EXP2(x) exp2f(x)
#endif

// ---------------------------------------------------------------------------
// Workspace layout (float slots):
//   wq_b  : bf16 [tap][oc][ic] 27*96*96 shorts  -> 124416 slots (r10 layout)
//   wk_b  : 124416
//   wv_b  : bf16 [oc][ic] 9216 shorts -> 4608
//   bias_q: 96, bias_k: 96 (fp32)
//   att   : fp32 [b][n][96]                     -> 983040
//   Qb    : bf16 [bh][n][32] (hd 24..31 zeroed) -> 655360
//   Kb    : bf16 [bh][n][32]                    -> 655360
//   Vtp   : bf16 [bh][tile][s*2+dh][16 dims][32 slots] — per-64-key-tile blocked
//   wo_b  : bf16 frag-blocked [oct 6][icb 3][j16 x 32ic] -> 4608 slots
// ---------------------------------------------------------------------------
#define WS_WQ   0
#define WS_WK   124416
#define WS_WV   248832
#define WS_BQ   253440
#define WS_BK   253536
#define WS_ATT  253632
#define WS_QB   1236672
#define WS_KB   1892032
#define WS_VT   2547392
#define WS_WO   3202752

__device__ __forceinline__ short f2bf(float f) {
    unsigned u = __float_as_uint(f);
    u += 0x7fffu + ((u >> 16) & 1u);
    return (short)(u >> 16);
}
__device__ __forceinline__ unsigned bf16pk(float lo, float hi) {
    unsigned r;
    asm("v_cvt_pk_bf16_f32 %0, %1, %2" : "=v"(r) : "v"(lo), "v"(hi));
    return r;
}
// PV slot of key n within its 64-token tile (bit5 = s-half kept, low 5 permuted
// so the P B-fragment is the lane's own QK^T output).
__device__ __forceinline__ int vslot(int n) {
    return (n & 32) | (((n >> 2) & 3) << 3) | (((n >> 4) & 1) << 2) | (n & 3);
}

// FUSED prep: one launch does all weight preprocessing.
//   blockIdx.y == 0: Q conv weights (TCDC+BN fold) + V 1x1x1 weights
//   blockIdx.y == 1: K conv weights
//   blockIdx.y == 2: wo -> fragment-blocked bf16
__global__ void prep_all(
        const float* __restrict__ wq, const float* __restrict__ bnq_g,
        const float* __restrict__ bnq_b, const float* __restrict__ bnq_m,
        const float* __restrict__ bnq_v,
        const float* __restrict__ wk, const float* __restrict__ bnk_g,
        const float* __restrict__ bnk_b, const float* __restrict__ bnk_m,
        const float* __restrict__ bnk_v,
        const float* __restrict__ wv, const float* __restrict__ wo,
        short* __restrict__ wq_b, short* __restrict__ wk_b,
        short* __restrict__ wv_b, short* __restrict__ wo_b,
        float* __restrict__ bias_q, float* __restrict__ bias_k) {
    const int y = blockIdx.y;
    if (y == 2) {
        int i = blockIdx.x * 128 + threadIdx.x;     // 96*128 = 12288 >= 9216
        if (i < CC * CC) {
            int oc = i / CC, ic = i % CC;
            wo_b[(((oc >> 4) * 3 + (ic >> 5)) << 9) + (oc & 15) * 32 + (ic & 31)] =
                f2bf(wo[i]);
        }
        return;
    }
    const float* w     = y ? wk    : wq;
    const float* gamma = y ? bnk_g : bnq_g;
    const float* beta  = y ? bnk_b : bnq_b;
    const float* mean  = y ? bnk_m : bnq_m;
    const float* var   = y ? bnk_v : bnq_v;
    short* w_eff = y ? wk_b : wq_b;
    float* bias  = y ? bias_k : bias_q;

    int oc = blockIdx.x;
    int ic = threadIdx.x;
    if (ic >= CC) return;
    float scale = gamma[oc] * rsqrtf(var[oc] + BN_EPS);
    if (ic == 0) bias[oc] = beta[oc] - mean[oc] * scale;
    const float* wp = w + (oc * CC + ic) * 27;
    float kdiff = 0.f;
#pragma unroll
    for (int t = 0; t < 9; ++t) kdiff += wp[t] + wp[18 + t];
#pragma unroll
    for (int t = 0; t < 27; ++t) {
        float v = wp[t];
        if (t == 13) v -= THETA * kdiff;     // center tap (1,1,1)
        w_eff[t * (CC * CC) + oc * CC + ic] = f2bf(v * scale);
    }
    if (y == 0) wv_b[oc * CC + ic] = f2bf(wv[oc * CC + ic]);
}

#define MFMA16(A, B, C) __builtin_amdgcn_mfma_f32_16x16x32_bf16(A, B, C, 0, 0, 0)

// MFMA im2col conv — r19 (proven-best, byte-identical): 2-tap-deep register
// weight pipeline; block = (2 depth slices) x (oc-half); 3 waves = oct(3).
__global__ __launch_bounds__(192) void qkv_conv(
        const float* __restrict__ x, const short* __restrict__ wq_b,
        const short* __restrict__ wk_b, const short* __restrict__ wv_b,
        const float* __restrict__ bias_q, const float* __restrict__ bias_k,
        const float* __restrict__ sgp,
        short* __restrict__ Qb, short* __restrict__ Kb, short* __restrict__ Vtp) {
    __shared__ __align__(16) short xs[65 * 104];   // 64 rows + zero row, stride 104
    const int b = blockIdx.y;
    const int d0 = blockIdx.x * 2;
    const int z = blockIdx.z;                       // oc-half
    const int tid = threadIdx.x;

    // stage 4 slices (d0-1 .. d0+2), f32 -> bf16 via cvt_pk; 1536 chunks
#pragma unroll
    for (int k = 0; k < 8; ++k) {
        int c = tid + k * 192;
        int row = c / 24, ic0 = (c % 24) * 4;
        int dg = d0 - 1 + (row >> 4), pos = row & 15;
        u32x2 o = {0u, 0u};
        if (dg >= 0 && dg < DEPTH) {
            f32x4 v = *(const f32x4*)(x + ((size_t)(b * NN + dg * 16 + pos)) * CC + ic0);
            o[0] = bf16pk(v[0], v[1]);
            o[1] = bf16pk(v[2], v[3]);
        }
        *(u32x2*)&xs[row * 104 + ic0] = o;
    }
    if (tid < 26) *(u32x2*)&xs[64 * 104 + tid * 4] = (u32x2){0u, 0u};
    __syncthreads();

    const int w  = tid >> 6, l = tid & 63;          // w = oct
    const int j  = l & 15, g = l >> 4;
    const int oc0 = z * 48 + w * 16;
    const int hj = j >> 2, wj = j & 3;

    const short* wqlane = wq_b + (oc0 + j) * CC + 8 * g;
    const short* wklane = wk_b + (oc0 + j) * CC + 8 * g;
    const short* wvlane = wv_b + (oc0 + j) * CC + 8 * g;

    f32x4 accQA = {0,0,0,0}, accQB = {0,0,0,0};
    f32x4 accKA = {0,0,0,0}, accKB = {0,0,0,0};
    f32x4 avA   = {0,0,0,0}, avB   = {0,0,0,0};

    // 3-slot register ring: taps t (compute), t+1, t+2 (in flight)
    s16x8 wq0[3], wk0[3], wq1[3], wk1[3], wq2[3], wk2[3];
#pragma unroll
    for (int icb = 0; icb < 3; ++icb) {
        wq0[icb] = *(const s16x8*)(wqlane + 0 * (CC * CC) + icb * 32);
        wk0[icb] = *(const s16x8*)(wklane + 0 * (CC * CC) + icb * 32);
        wq1[icb] = *(const s16x8*)(wqlane + 1 * (CC * CC) + icb * 32);
        wk1[icb] = *(const s16x8*)(wklane + 1 * (CC * CC) + icb * 32);
    }

#pragma unroll
    for (int tap = 0; tap < 27; ++tap) {
        if (tap < 25) {
#pragma unroll
            for (int icb = 0; icb < 3; ++icb) {
                wq2[icb] = *(const s16x8*)(wqlane + (tap + 2) * (CC * CC) + icb * 32);
                wk2[icb] = *(const s16x8*)(wklane + (tap + 2) * (CC * CC) + icb * 32);
            }
        }
        const int kd = tap / 9, kh = (tap / 3) % 3, kw = tap % 3;
        const int hh = hj + kh - 1, ww = wj + kw - 1;
        const bool valid = ((unsigned)hh < 4u) && ((unsigned)ww < 4u);
        const int rA = valid ? (kd * 16 + hh * 4 + ww) : 64;       // slice t=0
        const int rB = valid ? ((1 + kd) * 16 + hh * 4 + ww) : 64; // slice t=1
        const short* xrA = &xs[rA * 104 + 8 * g];
        const short* xrB = &xs[rB * 104 + 8 * g];
#pragma unroll
        for (int icb = 0; icb < 3; ++icb) {
            s16x8 afA = *(const s16x8*)(xrA + icb * 32);
            s16x8 afB = *(const s16x8*)(xrB + icb * 32);
            accQA = MFMA16(afA, wq0[icb], accQA);
            accQB = MFMA16(afB, wq0[icb], accQB);
            accKA = MFMA16(afA, wk0[icb], accKA);
            accKB = MFMA16(afB, wk0[icb], accKB);
            if (tap == 13) {   // V rides the center tap's A-frags
                s16x8 bv = *(const s16x8*)(wvlane + icb * 32);
                avA = MFMA16(afA, bv, avA);
                avB = MFMA16(afB, bv, avB);
            }
        }
        if (tap < 26) {
#pragma unroll
            for (int icb = 0; icb < 3; ++icb) {
                wq0[icb] = wq1[icb];
                wk0[icb] = wk1[icb];
                wq1[icb] = wq2[icb];
                wk1[icb] = wk2[icb];
            }
        }
    }

    // epilogue
    const float qs = 1.4426950408889634f / sgp[0];
    const int oc = oc0 + j, h = oc / HD, hd = oc % HD;
    const float bq_ = bias_q[oc], bk_ = bias_k[oc];
    const size_t headbase = (size_t)(b * NHH + h) * NN;
    short* QpA = Qb + (headbase + (d0 + 0) * 16 + 4 * g) * 32 + hd;
    short* QpB = Qb + (headbase + (d0 + 1) * 16 + 4 * g) * 32 + hd;
    short* KpA = Kb + (headbase + (d0 + 0) * 16 + 4 * g) * 32 + hd;
    short* KpB = Kb + (headbase + (d0 + 1) * 16 + 4 * g) * 32 + hd;
#pragma unroll
    for (int r = 0; r < 4; ++r) {
        QpA[r * 32] = f2bf((accQA[r] + bq_) * qs);
        QpB[r * 32] = f2bf((accQB[r] + bq_) * qs);
        KpA[r * 32] = f2bf(accKA[r] + bk_);
        KpB[r * 32] = f2bf(accKB[r] + bk_);
    }
    {
        short* Vb = Vtp + (size_t)(b * NHH + h) * (NN * 32);
        const int dh = hd >> 4, dj = hd & 15;
#pragma unroll
        for (int r = 0; r < 4; ++r) {
            int nA = d0 * 16 + 4 * g + r;
            int nB = nA + 16;
            int wA = vslot(nA & 63), wB = vslot(nB & 63);
            Vb[(nA >> 6) * 2048 + ((wA >> 5) * 2 + dh) * 512 + dj * 32 + (wA & 31)] = f2bf(avA[r]);
            Vb[(nB >> 6) * 2048 + ((wB >> 5) * 2 + dh) * 512 + dj * 32 + (wB & 31)] = f2bf(avB[r]);
        }
    }
    if (z == 0 && w == 0) {
        const int n = (d0 + ((l >> 4) & 1)) * 16 + (l & 15);
        const s16x8 z8 = {0, 0, 0, 0, 0, 0, 0, 0};
#pragma unroll
        for (int it = 0; it < 2; ++it) {
            int h2 = (l >> 5) + 2 * it;
            *(s16x8*)(Qb + ((size_t)(b * NHH + h2) * NN + n) * 32 + 24) = z8;
            *(s16x8*)(Kb + ((size_t)(b * NHH + h2) * NN + n) * 32 + 24) = z8;
        }
        const int wN = vslot(n & 63);
#pragma unroll
        for (int it2 = 0; it2 < 2; ++it2) {
            int h3 = it2 * 2 + (l >> 5);
            short* pb = Vtp + (size_t)(b * NHH + h3) * (NN * 32)
                      + (n >> 6) * 2048 + ((wN >> 5) * 2 + 1) * 512 + (wN & 31);
#pragma unroll
            for (int dj = 8; dj < 16; ++dj)
                pb[dj * 32] = 0;
        }
    }
}

// MFMA flash attention — r10 math + exact rescale-skip (r20-proven);
// K-SPLIT x8: 8 waves/block (512 thr), each wave 320 keys (5 tiles).
// Serial per-wave chain halves and wave supply doubles (attn was measured
// latency-limited: VALUBusy 60% at Occupancy 21%, r20). No unroll-2 (it
// cost VGPR 80 / occupancy). 8-way max-rebased LDS combine at the end.
#define SOFTTILE(S0, S1, S2, S3, MX, LP, OA, OB, P0, P1) {                      \
    float v0 = fmaxf(fmaxf(S0[0], S0[1]), fmaxf(S0[2], S0[3]));                 \
    float v1 = fmaxf(fmaxf(S1[0], S1[1]), fmaxf(S1[2], S1[3]));                 \
    float v2 = fmaxf(fmaxf(S2[0], S2[1]), fmaxf(S2[2], S2[3]));                 \
    float v3 = fmaxf(fmaxf(S3[0], S3[1]), fmaxf(S3[2], S3[3]));                 \
    float vmx = fmaxf(fmaxf(v0, v1), fmaxf(v2, v3));                            \
    vmx = fmaxf(vmx, __shfl_xor(vmx, 16));                                      \
    vmx = fmaxf(vmx, __shfl_xor(vmx, 32));                                      \
    if (__any(vmx > MX)) {                                                      \
        float nm = fmaxf(MX, vmx);                                              \
        float sc = EXP2(MX - nm);                                               \
        MX = nm;                                                                \
        LP *= sc; OA *= sc; OB *= sc;                                           \
    }                                                                           \
    float p00 = EXP2(S0[0] - MX), p01 = EXP2(S0[1] - MX);                       \
    float p02 = EXP2(S0[2] - MX), p03 = EXP2(S0[3] - MX);                       \
    float p10 = EXP2(S1[0] - MX), p11 = EXP2(S1[1] - MX);                       \
    float p12 = EXP2(S1[2] - MX), p13 = EXP2(S1[3] - MX);                       \
    float p20 = EXP2(S2[0] - MX), p21 = EXP2(S2[1] - MX);                       \
    float p22 = EXP2(S2[2] - MX), p23 = EXP2(S2[3] - MX);                       \
    float p30 = EXP2(S3[0] - MX), p31 = EXP2(S3[1] - MX);                       \
    float p32 = EXP2(S3[2] - MX), p33 = EXP2(S3[3] - MX);                       \
    LP += (((p00 + p01) + (p02 + p03)) + ((p10 + p11) + (p12 + p13)))           \
        + (((p20 + p21) + (p22 + p23)) + ((p30 + p31) + (p32 + p33)));          \
    u32x4 w0_ = { bf16pk(p00, p01), bf16pk(p02, p03),                           \
                  bf16pk(p10, p11), bf16pk(p12, p13) };                         \
    u32x4 w1_ = { bf16pk(p20, p21), bf16pk(p22, p23),                           \
                  bf16pk(p30, p31), bf16pk(p32, p33) };                         \
    P0 = __builtin_bit_cast(s16x8, w0_);                                        \
    P1 = __builtin_bit_cast(s16x8, w1_);                                        \
}

__global__ __launch_bounds__(512) void attn_kernel(
        const short* __restrict__ Qb, const short* __restrict__ Kb,
        const short* __restrict__ Vtp, float* __restrict__ att) {
    __shared__ __align__(16) float comb[7][64][20];   // 35.8 KB
    const int bh = blockIdx.x & 15;            // pins bh pairs per XCD for L2 reuse
    const int q0 = (blockIdx.x >> 4) * 32;
    const int b = bh >> 2, h = bh & 3;
    const int tid = threadIdx.x, wvid = tid >> 6, l = tid & 63;
    const int j = l & 15, g = l >> 4;

    const s16x8 qf0 = *(const s16x8*)(Qb + ((size_t)bh * NN + q0 + j) * 32 + 8 * g);
    const s16x8 qf1 = *(const s16x8*)(Qb + ((size_t)bh * NN + q0 + 16 + j) * 32 + 8 * g);
    const short* Kbase = Kb  + (size_t)bh * NN * 32 + (size_t)j * 32 + 8 * g;
    const short* Vbase = Vtp + (size_t)bh * NN * 32 + (size_t)j * 32 + 8 * g;

    f32x4 oA0 = {0,0,0,0}, oB0 = {0,0,0,0};    // q-tile 0: O^T dims 4g.. / 16+4g..
    f32x4 oA1 = {0,0,0,0}, oB1 = {0,0,0,0};    // q-tile 1
    float mx0 = -1e30f, lp0 = 0.f, mx1 = -1e30f, lp1 = 0.f;
    const f32x4 z = {0,0,0,0};

    const int tbeg = wvid * (NN / 8);
    const int tend = tbeg + NN / 8;            // 320 keys, 5 tiles per wave

    for (int t0 = tbeg; t0 < tend; t0 += 64) {
        const short* kp = Kbase + (size_t)t0 * 32;
        s16x8 k0 = *(const s16x8*)(kp);
        s16x8 k1 = *(const s16x8*)(kp + 512);
        s16x8 k2 = *(const s16x8*)(kp + 1024);
        s16x8 k3 = *(const s16x8*)(kp + 1536);
        const short* vp = Vbase + (size_t)t0 * 32;     // tile base: t0/64*2048
        s16x8 vA0 = *(const s16x8*)(vp);               // (s0,d0)
        s16x8 vB0 = *(const s16x8*)(vp + 512);         // (s0,d1)
        s16x8 vA1 = *(const s16x8*)(vp + 1024);        // (s1,d0)
        s16x8 vB1 = *(const s16x8*)(vp + 1536);        // (s1,d1)

        f32x4 s0 = __builtin_amdgcn_mfma_f32_16x16x32_bf16(k0, qf0, z, 0, 0, 0);
        f32x4 s1 = __builtin_amdgcn_mfma_f32_16x16x32_bf16(k1, qf0, z, 0, 0, 0);
        f32x4 s2 = __builtin_amdgcn_mfma_f32_16x16x32_bf16(k2, qf0, z, 0, 0, 0);
        f32x4 s3 = __builtin_amdgcn_mfma_f32_16x16x32_bf16(k3, qf0, z, 0, 0, 0);
        s16x8 P00, P01;
        SOFTTILE(s0, s1, s2, s3, mx0, lp0, oA0, oB0, P00, P01)

        f32x4 t0s = __builtin_amdgcn_mfma_f32_16x16x32_bf16(k0, qf1, z, 0, 0, 0);
        f32x4 t1s = __builtin_amdgcn_mfma_f32_16x16x32_bf16(k1, qf1, z, 0, 0, 0);
        f32x4 t2s = __builtin_amdgcn_mfma_f32_16x16x32_bf16(k2, qf1, z, 0, 0, 0);
        f32x4 t3s = __builtin_amdgcn_mfma_f32_16x16x32_bf16(k3, qf1, z, 0, 0, 0);
        s16x8 P10, P11;
        SOFTTILE(t0s, t1s, t2s, t3s, mx1, lp1, oA1, oB1, P10, P11)

        oA0 = __builtin_amdgcn_mfma_f32_16x16x32_bf16(vA0, P00, oA0, 0, 0, 0);
        oA0 = __builtin_amdgcn_mfma_f32_16x16x32_bf16(vA1, P01, oA0, 0, 0, 0);
        oB0 = __builtin_amdgcn_mfma_f32_16x16x32_bf16(vB0, P00, oB0, 0, 0, 0);
        oB0 = __builtin_amdgcn_mfma_f32_16x16x32_bf16(vB1, P01, oB0, 0, 0, 0);
        oA1 = __builtin_amdgcn_mfma_f32_16x16x32_bf16(vA0, P10, oA1, 0, 0, 0);
        oA1 = __builtin_amdgcn_mfma_f32_16x16x32_bf16(vA1, P11, oA1, 0, 0, 0);
        oB1 = __builtin_amdgcn_mfma_f32_16x16x32_bf16(vB0, P10, oB1, 0, 0, 0);
        oB1 = __builtin_amdgcn_mfma_f32_16x16x32_bf16(vB1, P11, oB1, 0, 0, 0);
    }

    // row-sum lp across the 4 g-lanes
    lp0 += __shfl_xor(lp0, 16); lp0 += __shfl_xor(lp0, 32);
    lp1 += __shfl_xor(lp1, 16); lp1 += __shfl_xor(lp1, 32);

    if (wvid != 0) {
        float* cp = comb[wvid - 1][l];
        cp[0] = mx0; cp[1] = lp0; cp[2] = mx1; cp[3] = lp1;
        *(f32x4*)(cp + 4)  = oA0;
        *(f32x4*)(cp + 8)  = oB0;
        *(f32x4*)(cp + 12) = oA1;
        *(f32x4*)(cp + 16) = oB1;
    }
    __syncthreads();
    if (wvid != 0) return;

    // 8-way max-rebased combine
#pragma unroll
    for (int wv = 0; wv < 7; ++wv) {
        const float* cp = comb[wv][l];
        {
            float mb = cp[0], lb = cp[1];
            f32x4 oAb = *(const f32x4*)(cp + 4);
            f32x4 oBb = *(const f32x4*)(cp + 8);
            float mm = fmaxf(mx0, mb);
            float sa = EXP2(mx0 - mm), sb = EXP2(mb - mm);
            mx0 = mm;
            lp0 = lp0 * sa + lb * sb;
            oA0 = oA0 * sa + oAb * sb;
            oB0 = oB0 * sa + oBb * sb;
        }
        {
            float mb = cp[2], lb = cp[3];
            f32x4 oAb = *(const f32x4*)(cp + 12);
            f32x4 oBb = *(const f32x4*)(cp + 16);
            float mm = fmaxf(mx1, mb);
            float sa = EXP2(mx1 - mm), sb = EXP2(mb - mm);
            mx1 = mm;
            lp1 = lp1 * sa + lb * sb;
            oA1 = oA1 * sa + oAb * sb;
            oB1 = oB1 * sa + oBb * sb;
        }
    }

    const float rl0 = 1.f / lp0, rl1 = 1.f / lp1;
    f32x4 rA0 = oA0 * rl0, rB0 = oB0 * rl0;
    f32x4 rA1 = oA1 * rl1, rB1 = oB1 * rl1;

    float* op0 = att + ((size_t)b * NN + q0 + j) * CC + h * HD;
    float* op1 = att + ((size_t)b * NN + q0 + 16 + j) * CC + h * HD;
    *(f32x4*)(op0 + 4 * g) = rA0;
    *(f32x4*)(op1 + 4 * g) = rA1;
    if (g < 2) {
        *(f32x4*)(op0 + 16 + 4 * g) = rB0;
        *(f32x4*)(op1 + 16 + 4 * g) = rB1;
    }
}

// MFMA out-projection — r16 (proven, byte-identical).
__global__ __launch_bounds__(256) void proj_kernel(
        const float* __restrict__ att, const short* __restrict__ wo_b,
        const float* __restrict__ bo, float* __restrict__ out) {
    __shared__ __align__(16) short als[64 * 104];
    const int t0 = blockIdx.x * 64;
    const int tid = threadIdx.x;
#pragma unroll
    for (int k = 0; k < 6; ++k) {
        int c = tid + k * 256;                      // 1536 chunks
        int row = c / 24, ic0 = (c % 24) * 4;
        f32x4 v = *(const f32x4*)(att + (size_t)(t0 + row) * CC + ic0);
        u32x2 o = { bf16pk(v[0], v[1]), bf16pk(v[2], v[3]) };
        *(u32x2*)&als[row * 104 + ic0] = o;
    }
    __syncthreads();

    const int w = tid >> 6, l = tid & 63;
    const int j = l & 15, g = l >> 4;
    const short* ap = &als[(w * 16 + j) * 104 + 8 * g];
    s16x8 a0 = *(const s16x8*)(ap);
    s16x8 a1 = *(const s16x8*)(ap + 32);
    s16x8 a2 = *(const s16x8*)(ap + 64);
    const f32x4 zz = {0, 0, 0, 0};
    float* ob = out + (size_t)(t0 + w * 16 + 4 * g) * CC + j;
#pragma unroll
    for (int oct = 0; oct < 6; ++oct) {
        const short* wp = wo_b + oct * 3 * 512 + j * 32 + 8 * g;
        f32x4 acc = zz;
        acc = __builtin_amdgcn_mfma_f32_16x16x32_bf16(a0, *(const s16x8*)(wp),        acc, 0, 0, 0);
        acc = __builtin_amdgcn_mfma_f32_16x16x32_bf16(a1, *(const s16x8*)(wp + 512),  acc, 0, 0, 0);
        acc = __builtin_amdgcn_mfma_f32_16x16x32_bf16(a2, *(const s16x8*)(wp + 1024), acc, 0, 0, 0);
        const float bb = bo[oct * 16 + j];
#pragma unroll
        for (int r = 0; r < 4; ++r)
            ob[(size_t)r * CC + oct * 16] = acc[r] + bb;
    }
}

extern "C" void kernel_launch(void* const* d_in, const int* in_sizes, int n_in,
                              void* d_out, int out_size, void* d_ws, size_t ws_size,
                              hipStream_t stream) {
    const float* x     = (const float*)d_in[0];
    const float* sg    = (const float*)d_in[1];
    const float* wq    = (const float*)d_in[2];
    const float* bnq_g = (const float*)d_in[3];
    const float* bnq_b = (const float*)d_in[4];
    const float* bnq_m = (const float*)d_in[5];
    const float* bnq_v = (const float*)d_in[6];
    const float* wk    = (const float*)d_in[7];
    const float* bnk_g = (const float*)d_in[8];
    const float* bnk_b = (const float*)d_in[9];
    const float* bnk_m = (const float*)d_in[10];
    const float* bnk_v = (const float*)d_in[11];
    const float* wv    = (const float*)d_in[12];
    const float* wo    = (const float*)d_in[13];
    const float* bo    = (const float*)d_in[14];

    float* ws = (float*)d_ws;
    short* wq_b   = (short*)(ws + WS_WQ);
    short* wk_b   = (short*)(ws + WS_WK);
    short* wv_b   = (short*)(ws + WS_WV);
    float* bias_q = ws + WS_BQ;
    float* bias_k = ws + WS_BK;
    float* attw   = ws + WS_ATT;
    short* Qb     = (short*)(ws + WS_QB);
    short* Kb     = (short*)(ws + WS_KB);
    short* Vtp    = (short*)(ws + WS_VT);
    short* wo_b   = (short*)(ws + WS_WO);

    prep_all<<<dim3(CC, 3), dim3(128), 0, stream>>>(
        wq, bnq_g, bnq_b, bnq_m, bnq_v,
        wk, bnk_g, bnk_b, bnk_m, bnk_v,
        wv, wo, wq_b, wk_b, wv_b, wo_b, bias_q, bias_k);

    qkv_conv<<<dim3(DEPTH / 2, BB, 2), dim3(192), 0, stream>>>(
        x, wq_b, wk_b, wv_b, bias_q, bias_k, sg, Qb, Kb, Vtp);

    attn_kernel<<<dim3(NN / 32 * 16), dim3(512), 0, stream>>>(Qb, Kb, Vtp, attw);

    proj_kernel<<<dim3(BB * NN / 64), dim3(256), 0, stream>>>(attw, wo_b, bo, (float*)d_out);
}

// Round 22
// 71.894 us; speedup vs baseline: 1.3047x; 1.0246x over previous
//
#include <hip/hip_runtime.h>
#include <hip/hip_bf16.h>

#define BB 4
#define DEPTH 160
#define CC 96
#define NN 2560          // DEPTH*16
#define NHH 4
#define HD 24
#define THETA 0.6f
#define BN_EPS 1e-5f

typedef __attribute__((ext_vector_type(4))) float f32x4;
typedef __attribute__((ext_vector_type(8))) short s16x8;
typedef __attribute__((ext_vector_type(4))) short s16x4;
typedef __attribute__((ext_vector_type(2))) unsigned u32x2;
typedef __attribute__((ext_vector_type(4))) unsigned u32x4;

#if __has_builtin(__builtin_amdgcn_exp2f)
#define EXP2(x) __builtin_amdgcn_exp2f(x)
#else
#define EXP2(x) exp2f(x)
#endif

// ---------------------------------------------------------------------------
// Workspace layout (float slots):
//   wq_b  : bf16 [tap][oc][ic] 27*96*96 shorts  -> 124416 slots (r10 layout)
//   wk_b  : 124416
//   wv_b  : bf16 [oc][ic] 9216 shorts -> 4608
//   bias_q: 96, bias_k: 96 (fp32)
//   att   : fp32 [b][n][96]                     -> 983040
//   Qb    : bf16 [bh][n][32] (hd 24..31 zeroed) -> 655360
//   Kb    : bf16 [bh][n][32]                    -> 655360
//   Vtp   : bf16 [bh][tile][s*2+dh][16 dims][32 slots] — per-64-key-tile blocked
//   wo_b  : bf16 frag-blocked [oct 6][icb 3][j16 x 32ic] -> 4608 slots
// ---------------------------------------------------------------------------
#define WS_WQ   0
#define WS_WK   124416
#define WS_WV   248832
#define WS_BQ   253440
#define WS_BK   253536
#define WS_ATT  253632
#define WS_QB   1236672
#define WS_KB   1892032
#define WS_VT   2547392
#define WS_WO   3202752

__device__ __forceinline__ short f2bf(float f) {
    unsigned u = __float_as_uint(f);
    u += 0x7fffu + ((u >> 16) & 1u);
    return (short)(u >> 16);
}
__device__ __forceinline__ unsigned bf16pk(float lo, float hi) {
    unsigned r;
    asm("v_cvt_pk_bf16_f32 %0, %1, %2" : "=v"(r) : "v"(lo), "v"(hi));
    return r;
}
// PV slot of key n within its 64-token tile (bit5 = s-half kept, low 5 permuted
// so the P B-fragment is the lane's own QK^T output).
__device__ __forceinline__ int vslot(int n) {
    return (n & 32) | (((n >> 2) & 3) << 3) | (((n >> 4) & 1) << 2) | (n & 3);
}

// FUSED prep: one launch does all weight preprocessing.
//   blockIdx.y == 0: Q conv weights (TCDC+BN fold) + V 1x1x1 weights
//   blockIdx.y == 1: K conv weights
//   blockIdx.y == 2: wo -> fragment-blocked bf16
__global__ void prep_all(
        const float* __restrict__ wq, const float* __restrict__ bnq_g,
        const float* __restrict__ bnq_b, const float* __restrict__ bnq_m,
        const float* __restrict__ bnq_v,
        const float* __restrict__ wk, const float* __restrict__ bnk_g,
        const float* __restrict__ bnk_b, const float* __restrict__ bnk_m,
        const float* __restrict__ bnk_v,
        const float* __restrict__ wv, const float* __restrict__ wo,
        short* __restrict__ wq_b, short* __restrict__ wk_b,
        short* __restrict__ wv_b, short* __restrict__ wo_b,
        float* __restrict__ bias_q, float* __restrict__ bias_k) {
    const int y = blockIdx.y;
    if (y == 2) {
        int i = blockIdx.x * 128 + threadIdx.x;     // 96*128 = 12288 >= 9216
        if (i < CC * CC) {
            int oc = i / CC, ic = i % CC;
            wo_b[(((oc >> 4) * 3 + (ic >> 5)) << 9) + (oc & 15) * 32 + (ic & 31)] =
                f2bf(wo[i]);
        }
        return;
    }
    const float* w     = y ? wk    : wq;
    const float* gamma = y ? bnk_g : bnq_g;
    const float* beta  = y ? bnk_b : bnq_b;
    const float* mean  = y ? bnk_m : bnq_m;
    const float* var   = y ? bnk_v : bnq_v;
    short* w_eff = y ? wk_b : wq_b;
    float* bias  = y ? bias_k : bias_q;

    int oc = blockIdx.x;
    int ic = threadIdx.x;
    if (ic >= CC) return;
    float scale = gamma[oc] * rsqrtf(var[oc] + BN_EPS);
    if (ic == 0) bias[oc] = beta[oc] - mean[oc] * scale;
    const float* wp = w + (oc * CC + ic) * 27;
    float kdiff = 0.f;
#pragma unroll
    for (int t = 0; t < 9; ++t) kdiff += wp[t] + wp[18 + t];
#pragma unroll
    for (int t = 0; t < 27; ++t) {
        float v = wp[t];
        if (t == 13) v -= THETA * kdiff;     // center tap (1,1,1)
        w_eff[t * (CC * CC) + oc * CC + ic] = f2bf(v * scale);
    }
    if (y == 0) wv_b[oc * CC + ic] = f2bf(wv[oc * CC + ic]);
}

#define MFMA16(A, B, C) __builtin_amdgcn_mfma_f32_16x16x32_bf16(A, B, C, 0, 0, 0)

// MFMA im2col conv — QK-SPLIT x RING (the untried quadrant): block = (2 depth
// slices) x (oc-half); 6 waves = qk(2) x oct(3), each wave computes only its
// Q-or-K output for one oc-tile across both token slices (per-wave weight
// stream HALVES to 3 loads/tap) with a 4-slot register ring at prefetch
// distance 3 (9 loads in flight ~ full L2 latency when combined with the
// doubled TLP of 3.75 waves/SIMD). Weight L2 traffic unchanged vs r19.
__global__ __launch_bounds__(384) void qkv_conv(
        const float* __restrict__ x, const short* __restrict__ wq_b,
        const short* __restrict__ wk_b, const short* __restrict__ wv_b,
        const float* __restrict__ bias_q, const float* __restrict__ bias_k,
        const float* __restrict__ sgp,
        short* __restrict__ Qb, short* __restrict__ Kb, short* __restrict__ Vtp) {
    __shared__ __align__(16) short xs[65 * 104];   // 64 rows + zero row, stride 104
    const int b = blockIdx.y;
    const int d0 = blockIdx.x * 2;
    const int z = blockIdx.z;                       // oc-half
    const int tid = threadIdx.x;

    // stage 4 slices (d0-1 .. d0+2), f32 -> bf16 via cvt_pk; 1536 chunks
#pragma unroll
    for (int k = 0; k < 4; ++k) {
        int c = tid + k * 384;
        int row = c / 24, ic0 = (c % 24) * 4;
        int dg = d0 - 1 + (row >> 4), pos = row & 15;
        u32x2 o = {0u, 0u};
        if (dg >= 0 && dg < DEPTH) {
            f32x4 v = *(const f32x4*)(x + ((size_t)(b * NN + dg * 16 + pos)) * CC + ic0);
            o[0] = bf16pk(v[0], v[1]);
            o[1] = bf16pk(v[2], v[3]);
        }
        *(u32x2*)&xs[row * 104 + ic0] = o;
    }
    if (tid < 26) *(u32x2*)&xs[64 * 104 + tid * 4] = (u32x2){0u, 0u};
    __syncthreads();

    const int w  = tid >> 6, l = tid & 63;
    const int qk = w / 3, oct = w % 3;
    const int j  = l & 15, g = l >> 4;
    const int oc0 = z * 48 + oct * 16;
    const int hj = j >> 2, wj = j & 3;

    const short* wlane  = (qk ? wk_b : wq_b) + (oc0 + j) * CC + 8 * g;
    const short* wvlane = wv_b + (oc0 + j) * CC + 8 * g;

    f32x4 accA = {0,0,0,0}, accB = {0,0,0,0};
    f32x4 avA  = {0,0,0,0}, avB  = {0,0,0,0};

    // 4-slot ring: tap t (compute) + t+1, t+2, t+3 in flight
    s16x8 s0_[3], s1_[3], s2_[3], s3_[3];
#pragma unroll
    for (int icb = 0; icb < 3; ++icb) {
        s0_[icb] = *(const s16x8*)(wlane + 0 * (CC * CC) + icb * 32);
        s1_[icb] = *(const s16x8*)(wlane + 1 * (CC * CC) + icb * 32);
        s2_[icb] = *(const s16x8*)(wlane + 2 * (CC * CC) + icb * 32);
    }

#pragma unroll
    for (int tap = 0; tap < 27; ++tap) {
        if (tap < 24) {
#pragma unroll
            for (int icb = 0; icb < 3; ++icb)
                s3_[icb] = *(const s16x8*)(wlane + (tap + 3) * (CC * CC) + icb * 32);
        }
        const int kd = tap / 9, kh = (tap / 3) % 3, kw = tap % 3;
        const int hh = hj + kh - 1, ww = wj + kw - 1;
        const bool valid = ((unsigned)hh < 4u) && ((unsigned)ww < 4u);
        const int rA = valid ? (kd * 16 + hh * 4 + ww) : 64;       // slice t=0
        const int rB = valid ? ((1 + kd) * 16 + hh * 4 + ww) : 64; // slice t=1
        const short* xrA = &xs[rA * 104 + 8 * g];
        const short* xrB = &xs[rB * 104 + 8 * g];
#pragma unroll
        for (int icb = 0; icb < 3; ++icb) {
            s16x8 afA = *(const s16x8*)(xrA + icb * 32);
            s16x8 afB = *(const s16x8*)(xrB + icb * 32);
            accA = MFMA16(afA, s0_[icb], accA);
            accB = MFMA16(afB, s0_[icb], accB);
            if (tap == 13 && qk == 0) {   // V rides center tap on Q-waves
                s16x8 bv = *(const s16x8*)(wvlane + icb * 32);
                avA = MFMA16(afA, bv, avA);
                avB = MFMA16(afB, bv, avB);
            }
        }
        if (tap < 26) {
#pragma unroll
            for (int icb = 0; icb < 3; ++icb) {
                s0_[icb] = s1_[icb];
                s1_[icb] = s2_[icb];
                s2_[icb] = s3_[icb];
            }
        }
    }

    // epilogue (per-qk: Q-waves write Qb+Vtp, K-waves write Kb)
    const float qs = 1.4426950408889634f / sgp[0];
    const int oc = oc0 + j, h = oc / HD, hd = oc % HD;
    const float bb_ = qk ? bias_k[oc] : bias_q[oc];
    const size_t headbase = (size_t)(b * NHH + h) * NN;
    short* base = (qk ? Kb : Qb) + (headbase) * 32 + hd;
    short* ObA = base + (size_t)((d0 + 0) * 16 + 4 * g) * 32;
    short* ObB = base + (size_t)((d0 + 1) * 16 + 4 * g) * 32;
#pragma unroll
    for (int r = 0; r < 4; ++r) {
        float vA = accA[r] + bb_, vB = accB[r] + bb_;
        if (!qk) { vA *= qs; vB *= qs; }
        ObA[r * 32] = f2bf(vA);
        ObB[r * 32] = f2bf(vB);
    }
    if (qk == 0) {
        short* Vb = Vtp + (size_t)(b * NHH + h) * (NN * 32);
        const int dh = hd >> 4, dj = hd & 15;
#pragma unroll
        for (int r = 0; r < 4; ++r) {
            int nA = d0 * 16 + 4 * g + r;
            int nB = nA + 16;
            int wA = vslot(nA & 63), wB = vslot(nB & 63);
            Vb[(nA >> 6) * 2048 + ((wA >> 5) * 2 + dh) * 512 + dj * 32 + (wA & 31)] = f2bf(avA[r]);
            Vb[(nB >> 6) * 2048 + ((wB >> 5) * 2 + dh) * 512 + dj * 32 + (wB & 31)] = f2bf(avB[r]);
        }
    }
    // pads once per token-block (z==0, oct==0; both qk waves):
    //   Qb/Kb hd 24..31 (own array per qk); Vtp pad dims 24..31 (heads split by qk)
    if (z == 0 && oct == 0) {
        const int n = (d0 + ((l >> 4) & 1)) * 16 + (l & 15);
        const s16x8 z8 = {0, 0, 0, 0, 0, 0, 0, 0};
        short* arr = qk ? Kb : Qb;
#pragma unroll
        for (int it = 0; it < 2; ++it) {
            int h2 = (l >> 5) + 2 * it;
            *(s16x8*)(arr + ((size_t)(b * NHH + h2) * NN + n) * 32 + 24) = z8;
        }
        const int h3 = qk * 2 + (l >> 5);     // qk=0: heads 0,1; qk=1: heads 2,3
        const int wN = vslot(n & 63);
        short* pb = Vtp + (size_t)(b * NHH + h3) * (NN * 32)
                  + (n >> 6) * 2048 + ((wN >> 5) * 2 + 1) * 512 + (wN & 31);
#pragma unroll
        for (int dj = 8; dj < 16; ++dj)
            pb[dj * 32] = 0;
    }
}

// MFMA flash attention — r21 (proven, byte-identical): r10 math + exact
// rescale-skip; K-split x8, 8-way max-rebased LDS combine.
#define SOFTTILE(S0, S1, S2, S3, MX, LP, OA, OB, P0, P1) {                      \
    float v0 = fmaxf(fmaxf(S0[0], S0[1]), fmaxf(S0[2], S0[3]));                 \
    float v1 = fmaxf(fmaxf(S1[0], S1[1]), fmaxf(S1[2], S1[3]));                 \
    float v2 = fmaxf(fmaxf(S2[0], S2[1]), fmaxf(S2[2], S2[3]));                 \
    float v3 = fmaxf(fmaxf(S3[0], S3[1]), fmaxf(S3[2], S3[3]));                 \
    float vmx = fmaxf(fmaxf(v0, v1), fmaxf(v2, v3));                            \
    vmx = fmaxf(vmx, __shfl_xor(vmx, 16));                                      \
    vmx = fmaxf(vmx, __shfl_xor(vmx, 32));                                      \
    if (__any(vmx > MX)) {                                                      \
        float nm = fmaxf(MX, vmx);                                              \
        float sc = EXP2(MX - nm);                                               \
        MX = nm;                                                                \
        LP *= sc; OA *= sc; OB *= sc;                                           \
    }                                                                           \
    float p00 = EXP2(S0[0] - MX), p01 = EXP2(S0[1] - MX);                       \
    float p02 = EXP2(S0[2] - MX), p03 = EXP2(S0[3] - MX);                       \
    float p10 = EXP2(S1[0] - MX), p11 = EXP2(S1[1] - MX);                       \
    float p12 = EXP2(S1[2] - MX), p13 = EXP2(S1[3] - MX);                       \
    float p20 = EXP2(S2[0] - MX), p21 = EXP2(S2[1] - MX);                       \
    float p22 = EXP2(S2[2] - MX), p23 = EXP2(S2[3] - MX);                       \
    float p30 = EXP2(S3[0] - MX), p31 = EXP2(S3[1] - MX);                       \
    float p32 = EXP2(S3[2] - MX), p33 = EXP2(S3[3] - MX);                       \
    LP += (((p00 + p01) + (p02 + p03)) + ((p10 + p11) + (p12 + p13)))           \
        + (((p20 + p21) + (p22 + p23)) + ((p30 + p31) + (p32 + p33)));          \
    u32x4 w0_ = { bf16pk(p00, p01), bf16pk(p02, p03),                           \
                  bf16pk(p10, p11), bf16pk(p12, p13) };                         \
    u32x4 w1_ = { bf16pk(p20, p21), bf16pk(p22, p23),                           \
                  bf16pk(p30, p31), bf16pk(p32, p33) };                         \
    P0 = __builtin_bit_cast(s16x8, w0_);                                        \
    P1 = __builtin_bit_cast(s16x8, w1_);                                        \
}

__global__ __launch_bounds__(512) void attn_kernel(
        const short* __restrict__ Qb, const short* __restrict__ Kb,
        const short* __restrict__ Vtp, float* __restrict__ att) {
    __shared__ __align__(16) float comb[7][64][20];   // 35.8 KB
    const int bh = blockIdx.x & 15;            // pins bh pairs per XCD for L2 reuse
    const int q0 = (blockIdx.x >> 4) * 32;
    const int b = bh >> 2, h = bh & 3;
    const int tid = threadIdx.x, wvid = tid >> 6, l = tid & 63;
    const int j = l & 15, g = l >> 4;

    const s16x8 qf0 = *(const s16x8*)(Qb + ((size_t)bh * NN + q0 + j) * 32 + 8 * g);
    const s16x8 qf1 = *(const s16x8*)(Qb + ((size_t)bh * NN + q0 + 16 + j) * 32 + 8 * g);
    const short* Kbase = Kb  + (size_t)bh * NN * 32 + (size_t)j * 32 + 8 * g;
    const short* Vbase = Vtp + (size_t)bh * NN * 32 + (size_t)j * 32 + 8 * g;

    f32x4 oA0 = {0,0,0,0}, oB0 = {0,0,0,0};    // q-tile 0: O^T dims 4g.. / 16+4g..
    f32x4 oA1 = {0,0,0,0}, oB1 = {0,0,0,0};    // q-tile 1
    float mx0 = -1e30f, lp0 = 0.f, mx1 = -1e30f, lp1 = 0.f;
    const f32x4 z = {0,0,0,0};

    const int tbeg = wvid * (NN / 8);
    const int tend = tbeg + NN / 8;            // 320 keys, 5 tiles per wave

    for (int t0 = tbeg; t0 < tend; t0 += 64) {
        const short* kp = Kbase + (size_t)t0 * 32;
        s16x8 k0 = *(const s16x8*)(kp);
        s16x8 k1 = *(const s16x8*)(kp + 512);
        s16x8 k2 = *(const s16x8*)(kp + 1024);
        s16x8 k3 = *(const s16x8*)(kp + 1536);
        const short* vp = Vbase + (size_t)t0 * 32;     // tile base: t0/64*2048
        s16x8 vA0 = *(const s16x8*)(vp);               // (s0,d0)
        s16x8 vB0 = *(const s16x8*)(vp + 512);         // (s0,d1)
        s16x8 vA1 = *(const s16x8*)(vp + 1024);        // (s1,d0)
        s16x8 vB1 = *(const s16x8*)(vp + 1536);        // (s1,d1)

        f32x4 s0 = __builtin_amdgcn_mfma_f32_16x16x32_bf16(k0, qf0, z, 0, 0, 0);
        f32x4 s1 = __builtin_amdgcn_mfma_f32_16x16x32_bf16(k1, qf0, z, 0, 0, 0);
        f32x4 s2 = __builtin_amdgcn_mfma_f32_16x16x32_bf16(k2, qf0, z, 0, 0, 0);
        f32x4 s3 = __builtin_amdgcn_mfma_f32_16x16x32_bf16(k3, qf0, z, 0, 0, 0);
        s16x8 P00, P01;
        SOFTTILE(s0, s1, s2, s3, mx0, lp0, oA0, oB0, P00, P01)

        f32x4 t0s = __builtin_amdgcn_mfma_f32_16x16x32_bf16(k0, qf1, z, 0, 0, 0);
        f32x4 t1s = __builtin_amdgcn_mfma_f32_16x16x32_bf16(k1, qf1, z, 0, 0, 0);
        f32x4 t2s = __builtin_amdgcn_mfma_f32_16x16x32_bf16(k2, qf1, z, 0, 0, 0);
        f32x4 t3s = __builtin_amdgcn_mfma_f32_16x16x32_bf16(k3, qf1, z, 0, 0, 0);
        s16x8 P10, P11;
        SOFTTILE(t0s, t1s, t2s, t3s, mx1, lp1, oA1, oB1, P10, P11)

        oA0 = __builtin_amdgcn_mfma_f32_16x16x32_bf16(vA0, P00, oA0, 0, 0, 0);
        oA0 = __builtin_amdgcn_mfma_f32_16x16x32_bf16(vA1, P01, oA0, 0, 0, 0);
        oB0 = __builtin_amdgcn_mfma_f32_16x16x32_bf16(vB0, P00, oB0, 0, 0, 0);
        oB0 = __builtin_amdgcn_mfma_f32_16x16x32_bf16(vB1, P01, oB0, 0, 0, 0);
        oA1 = __builtin_amdgcn_mfma_f32_16x16x32_bf16(vA0, P10, oA1, 0, 0, 0);
        oA1 = __builtin_amdgcn_mfma_f32_16x16x32_bf16(vA1, P11, oA1, 0, 0, 0);
        oB1 = __builtin_amdgcn_mfma_f32_16x16x32_bf16(vB0, P10, oB1, 0, 0, 0);
        oB1 = __builtin_amdgcn_mfma_f32_16x16x32_bf16(vB1, P11, oB1, 0, 0, 0);
    }

    // row-sum lp across the 4 g-lanes
    lp0 += __shfl_xor(lp0, 16); lp0 += __shfl_xor(lp0, 32);
    lp1 += __shfl_xor(lp1, 16); lp1 += __shfl_xor(lp1, 32);

    if (wvid != 0) {
        float* cp = comb[wvid - 1][l];
        cp[0] = mx0; cp[1] = lp0; cp[2] = mx1; cp[3] = lp1;
        *(f32x4*)(cp + 4)  = oA0;
        *(f32x4*)(cp + 8)  = oB0;
        *(f32x4*)(cp + 12) = oA1;
        *(f32x4*)(cp + 16) = oB1;
    }
    __syncthreads();
    if (wvid != 0) return;

    // 8-way max-rebased combine
#pragma unroll
    for (int wv = 0; wv < 7; ++wv) {
        const float* cp = comb[wv][l];
        {
            float mb = cp[0], lb = cp[1];
            f32x4 oAb = *(const f32x4*)(cp + 4);
            f32x4 oBb = *(const f32x4*)(cp + 8);
            float mm = fmaxf(mx0, mb);
            float sa = EXP2(mx0 - mm), sb = EXP2(mb - mm);
            mx0 = mm;
            lp0 = lp0 * sa + lb * sb;
            oA0 = oA0 * sa + oAb * sb;
            oB0 = oB0 * sa + oBb * sb;
        }
        {
            float mb = cp[2], lb = cp[3];
            f32x4 oAb = *(const f32x4*)(cp + 12);
            f32x4 oBb = *(const f32x4*)(cp + 16);
            float mm = fmaxf(mx1, mb);
            float sa = EXP2(mx1 - mm), sb = EXP2(mb - mm);
            mx1 = mm;
            lp1 = lp1 * sa + lb * sb;
            oA1 = oA1 * sa + oAb * sb;
            oB1 = oB1 * sa + oBb * sb;
        }
    }

    const float rl0 = 1.f / lp0, rl1 = 1.f / lp1;
    f32x4 rA0 = oA0 * rl0, rB0 = oB0 * rl0;
    f32x4 rA1 = oA1 * rl1, rB1 = oB1 * rl1;

    float* op0 = att + ((size_t)b * NN + q0 + j) * CC + h * HD;
    float* op1 = att + ((size_t)b * NN + q0 + 16 + j) * CC + h * HD;
    *(f32x4*)(op0 + 4 * g) = rA0;
    *(f32x4*)(op1 + 4 * g) = rA1;
    if (g < 2) {
        *(f32x4*)(op0 + 16 + 4 * g) = rB0;
        *(f32x4*)(op1 + 16 + 4 * g) = rB1;
    }
}

// MFMA out-projection — r16 (proven, byte-identical).
__global__ __launch_bounds__(256) void proj_kernel(
        const float* __restrict__ att, const short* __restrict__ wo_b,
        const float* __restrict__ bo, float* __restrict__ out) {
    __shared__ __align__(16) short als[64 * 104];
    const int t0 = blockIdx.x * 64;
    const int tid = threadIdx.x;
#pragma unroll
    for (int k = 0; k < 6; ++k) {
        int c = tid + k * 256;                      // 1536 chunks
        int row = c / 24, ic0 = (c % 24) * 4;
        f32x4 v = *(const f32x4*)(att + (size_t)(t0 + row) * CC + ic0);
        u32x2 o = { bf16pk(v[0], v[1]), bf16pk(v[2], v[3]) };
        *(u32x2*)&als[row * 104 + ic0] = o;
    }
    __syncthreads();

    const int w = tid >> 6, l = tid & 63;
    const int j = l & 15, g = l >> 4;
    const short* ap = &als[(w * 16 + j) * 104 + 8 * g];
    s16x8 a0 = *(const s16x8*)(ap);
    s16x8 a1 = *(const s16x8*)(ap + 32);
    s16x8 a2 = *(const s16x8*)(ap + 64);
    const f32x4 zz = {0, 0, 0, 0};
    float* ob = out + (size_t)(t0 + w * 16 + 4 * g) * CC + j;
#pragma unroll
    for (int oct = 0; oct < 6; ++oct) {
        const short* wp = wo_b + oct * 3 * 512 + j * 32 + 8 * g;
        f32x4 acc = zz;
        acc = __builtin_amdgcn_mfma_f32_16x16x32_bf16(a0, *(const s16x8*)(wp),        acc, 0, 0, 0);
        acc = __builtin_amdgcn_mfma_f32_16x16x32_bf16(a1, *(const s16x8*)(wp + 512),  acc, 0, 0, 0);
        acc = __builtin_amdgcn_mfma_f32_16x16x32_bf16(a2, *(const s16x8*)(wp + 1024), acc, 0, 0, 0);
        const float bb = bo[oct * 16 + j];
#pragma unroll
        for (int r = 0; r < 4; ++r)
            ob[(size_t)r * CC + oct * 16] = acc[r] + bb;
    }
}

extern "C" void kernel_launch(void* const* d_in, const int* in_sizes, int n_in,
                              void* d_out, int out_size, void* d_ws, size_t ws_size,
                              hipStream_t stream) {
    const float* x     = (const float*)d_in[0];
    const float* sg    = (const float*)d_in[1];
    const float* wq    = (const float*)d_in[2];
    const float* bnq_g = (const float*)d_in[3];
    const float* bnq_b = (const float*)d_in[4];
    const float* bnq_m = (const float*)d_in[5];
    const float* bnq_v = (const float*)d_in[6];
    const float* wk    = (const float*)d_in[7];
    const float* bnk_g = (const float*)d_in[8];
    const float* bnk_b = (const float*)d_in[9];
    const float* bnk_m = (const float*)d_in[10];
    const float* bnk_v = (const float*)d_in[11];
    const float* wv    = (const float*)d_in[12];
    const float* wo    = (const float*)d_in[13];
    const float* bo    = (const float*)d_in[14];

    float* ws = (float*)d_ws;
    short* wq_b   = (short*)(ws + WS_WQ);
    short* wk_b   = (short*)(ws + WS_WK);
    short* wv_b   = (short*)(ws + WS_WV);
    float* bias_q = ws + WS_BQ;
    float* bias_k = ws + WS_BK;
    float* attw   = ws + WS_ATT;
    short* Qb     = (short*)(ws + WS_QB);
    short* Kb     = (short*)(ws + WS_KB);
    short* Vtp    = (short*)(ws + WS_VT);
    short* wo_b   = (short*)(ws + WS_WO);

    prep_all<<<dim3(CC, 3), dim3(128), 0, stream>>>(
        wq, bnq_g, bnq_b, bnq_m, bnq_v,
        wk, bnk_g, bnk_b, bnk_m, bnk_v,
        wv, wo, wq_b, wk_b, wv_b, wo_b, bias_q, bias_k);

    qkv_conv<<<dim3(DEPTH / 2, BB, 2), dim3(384), 0, stream>>>(
        x, wq_b, wk_b, wv_b, bias_q, bias_k, sg, Qb, Kb, Vtp);

    attn_kernel<<<dim3(NN / 32 * 16), dim3(512), 0, stream>>>(Qb, Kb, Vtp, attw);

    proj_kernel<<<dim3(BB * NN / 64), dim3(256), 0, stream>>>(attw, wo_b, bo, (float*)d_out);
}

// Round 24
// 71.636 us; speedup vs baseline: 1.3094x; 1.0036x over previous
//
#include <hip/hip_runtime.h>
#include <hip/hip_bf16.h>

#define BB 4
#define DEPTH 160
#define CC 96
#define NN 2560          // DEPTH*16
#define NHH 4
#define HD 24
#define THETA 0.6f
#define BN_EPS 1e-5f

typedef __attribute__((ext_vector_type(4))) float f32x4;
typedef __attribute__((ext_vector_type(8))) short s16x8;
typedef __attribute__((ext_vector_type(4))) short s16x4;
typedef __attribute__((ext_vector_type(2))) unsigned u32x2;
typedef __attribute__((ext_vector_type(4))) unsigned u32x4;

#if __has_builtin(__builtin_amdgcn_exp2f)
#define EXP2(x) __builtin_amdgcn_exp2f(x)
#else
#define EXP2(x) exp2f(x)
#endif

// ---------------------------------------------------------------------------
// Workspace layout (float slots):
//   wq_b  : bf16 [tap][oc][ic] 27*96*96 shorts  -> 124416 slots (r10 layout)
//   wk_b  : 124416
//   wv_b  : bf16 [oc][ic] 9216 shorts -> 4608
//   bias_q: 96, bias_k: 96 (fp32)
//   att   : fp32 [b][n][96]                     -> 983040
//   Qb    : bf16 [bh][n][32] (hd 24..31 zeroed) -> 655360
//   Kb    : bf16 [bh][n][32]                    -> 655360
//   Vtp   : bf16 [bh][tile][s*2+dh][16 dims][32 slots] — per-64-key-tile blocked
//   wo_b  : bf16 frag-blocked [oct 6][icb 3][j16 x 32ic] -> 4608 slots
// ---------------------------------------------------------------------------
#define WS_WQ   0
#define WS_WK   124416
#define WS_WV   248832
#define WS_BQ   253440
#define WS_BK   253536
#define WS_ATT  253632
#define WS_QB   1236672
#define WS_KB   1892032
#define WS_VT   2547392
#define WS_WO   3202752

__device__ __forceinline__ short f2bf(float f) {
    unsigned u = __float_as_uint(f);
    u += 0x7fffu + ((u >> 16) & 1u);
    return (short)(u >> 16);
}
__device__ __forceinline__ unsigned bf16pk(float lo, float hi) {
    unsigned r;
    asm("v_cvt_pk_bf16_f32 %0, %1, %2" : "=v"(r) : "v"(lo), "v"(hi));
    return r;
}
// PV slot of key n within its 64-token tile (bit5 = s-half kept, low 5 permuted
// so the P B-fragment is the lane's own QK^T output).
__device__ __forceinline__ int vslot(int n) {
    return (n & 32) | (((n >> 2) & 3) << 3) | (((n >> 4) & 1) << 2) | (n & 3);
}

// FUSED prep: one launch does all weight preprocessing.
//   blockIdx.y == 0: Q conv weights (TCDC+BN fold) + V 1x1x1 weights
//   blockIdx.y == 1: K conv weights
//   blockIdx.y == 2: wo -> fragment-blocked bf16
__global__ void prep_all(
        const float* __restrict__ wq, const float* __restrict__ bnq_g,
        const float* __restrict__ bnq_b, const float* __restrict__ bnq_m,
        const float* __restrict__ bnq_v,
        const float* __restrict__ wk, const float* __restrict__ bnk_g,
        const float* __restrict__ bnk_b, const float* __restrict__ bnk_m,
        const float* __restrict__ bnk_v,
        const float* __restrict__ wv, const float* __restrict__ wo,
        short* __restrict__ wq_b, short* __restrict__ wk_b,
        short* __restrict__ wv_b, short* __restrict__ wo_b,
        float* __restrict__ bias_q, float* __restrict__ bias_k) {
    const int y = blockIdx.y;
    if (y == 2) {
        int i = blockIdx.x * 128 + threadIdx.x;     // 96*128 = 12288 >= 9216
        if (i < CC * CC) {
            int oc = i / CC, ic = i % CC;
            wo_b[(((oc >> 4) * 3 + (ic >> 5)) << 9) + (oc & 15) * 32 + (ic & 31)] =
                f2bf(wo[i]);
        }
        return;
    }
    const float* w     = y ? wk    : wq;
    const float* gamma = y ? bnk_g : bnq_g;
    const float* beta  = y ? bnk_b : bnq_b;
    const float* mean  = y ? bnk_m : bnq_m;
    const float* var   = y ? bnk_v : bnq_v;
    short* w_eff = y ? wk_b : wq_b;
    float* bias  = y ? bias_k : bias_q;

    int oc = blockIdx.x;
    int ic = threadIdx.x;
    if (ic >= CC) return;
    float scale = gamma[oc] * rsqrtf(var[oc] + BN_EPS);
    if (ic == 0) bias[oc] = beta[oc] - mean[oc] * scale;
    const float* wp = w + (oc * CC + ic) * 27;
    float kdiff = 0.f;
#pragma unroll
    for (int t = 0; t < 9; ++t) kdiff += wp[t] + wp[18 + t];
#pragma unroll
    for (int t = 0; t < 27; ++t) {
        float v = wp[t];
        if (t == 13) v -= THETA * kdiff;     // center tap (1,1,1)
        w_eff[t * (CC * CC) + oc * CC + ic] = f2bf(v * scale);
    }
    if (y == 0) wv_b[oc * CC + ic] = f2bf(wv[oc * CC + ic]);
}

#define MFMA16(A, B, C) __builtin_amdgcn_mfma_f32_16x16x32_bf16(A, B, C, 0, 0, 0)

// MFMA im2col conv — QK-SPLIT x RING (r22-proven): block = (2 depth slices) x
// (oc-half); 6 waves = qk(2) x oct(3); 4-slot register ring, distance 3.
__global__ __launch_bounds__(384) void qkv_conv(
        const float* __restrict__ x, const short* __restrict__ wq_b,
        const short* __restrict__ wk_b, const short* __restrict__ wv_b,
        const float* __restrict__ bias_q, const float* __restrict__ bias_k,
        const float* __restrict__ sgp,
        short* __restrict__ Qb, short* __restrict__ Kb, short* __restrict__ Vtp) {
    __shared__ __align__(16) short xs[65 * 104];   // 64 rows + zero row, stride 104
    const int b = blockIdx.y;
    const int d0 = blockIdx.x * 2;
    const int z = blockIdx.z;                       // oc-half
    const int tid = threadIdx.x;

    // stage 4 slices (d0-1 .. d0+2), f32 -> bf16 via cvt_pk; 1536 chunks
#pragma unroll
    for (int k = 0; k < 4; ++k) {
        int c = tid + k * 384;
        int row = c / 24, ic0 = (c % 24) * 4;
        int dg = d0 - 1 + (row >> 4), pos = row & 15;
        u32x2 o = {0u, 0u};
        if (dg >= 0 && dg < DEPTH) {
            f32x4 v = *(const f32x4*)(x + ((size_t)(b * NN + dg * 16 + pos)) * CC + ic0);
            o[0] = bf16pk(v[0], v[1]);
            o[1] = bf16pk(v[2], v[3]);
        }
        *(u32x2*)&xs[row * 104 + ic0] = o;
    }
    if (tid < 26) *(u32x2*)&xs[64 * 104 + tid * 4] = (u32x2){0u, 0u};
    __syncthreads();

    const int w  = tid >> 6, l = tid & 63;
    const int qk = w / 3, oct = w % 3;
    const int j  = l & 15, g = l >> 4;
    const int oc0 = z * 48 + oct * 16;
    const int hj = j >> 2, wj = j & 3;

    const short* wlane  = (qk ? wk_b : wq_b) + (oc0 + j) * CC + 8 * g;
    const short* wvlane = wv_b + (oc0 + j) * CC + 8 * g;

    f32x4 accA = {0,0,0,0}, accB = {0,0,0,0};
    f32x4 avA  = {0,0,0,0}, avB  = {0,0,0,0};

    // 4-slot ring: tap t (compute) + t+1, t+2, t+3 in flight
    s16x8 s0_[3], s1_[3], s2_[3], s3_[3];
#pragma unroll
    for (int icb = 0; icb < 3; ++icb) {
        s0_[icb] = *(const s16x8*)(wlane + 0 * (CC * CC) + icb * 32);
        s1_[icb] = *(const s16x8*)(wlane + 1 * (CC * CC) + icb * 32);
        s2_[icb] = *(const s16x8*)(wlane + 2 * (CC * CC) + icb * 32);
    }

#pragma unroll
    for (int tap = 0; tap < 27; ++tap) {
        if (tap < 24) {
#pragma unroll
            for (int icb = 0; icb < 3; ++icb)
                s3_[icb] = *(const s16x8*)(wlane + (tap + 3) * (CC * CC) + icb * 32);
        }
        const int kd = tap / 9, kh = (tap / 3) % 3, kw = tap % 3;
        const int hh = hj + kh - 1, ww = wj + kw - 1;
        const bool valid = ((unsigned)hh < 4u) && ((unsigned)ww < 4u);
        const int rA = valid ? (kd * 16 + hh * 4 + ww) : 64;       // slice t=0
        const int rB = valid ? ((1 + kd) * 16 + hh * 4 + ww) : 64; // slice t=1
        const short* xrA = &xs[rA * 104 + 8 * g];
        const short* xrB = &xs[rB * 104 + 8 * g];
#pragma unroll
        for (int icb = 0; icb < 3; ++icb) {
            s16x8 afA = *(const s16x8*)(xrA + icb * 32);
            s16x8 afB = *(const s16x8*)(xrB + icb * 32);
            accA = MFMA16(afA, s0_[icb], accA);
            accB = MFMA16(afB, s0_[icb], accB);
            if (tap == 13 && qk == 0) {   // V rides center tap on Q-waves
                s16x8 bv = *(const s16x8*)(wvlane + icb * 32);
                avA = MFMA16(afA, bv, avA);
                avB = MFMA16(afB, bv, avB);
            }
        }
        if (tap < 26) {
#pragma unroll
            for (int icb = 0; icb < 3; ++icb) {
                s0_[icb] = s1_[icb];
                s1_[icb] = s2_[icb];
                s2_[icb] = s3_[icb];
            }
        }
    }

    // epilogue (per-qk: Q-waves write Qb+Vtp, K-waves write Kb)
    const float qs = 1.4426950408889634f / sgp[0];
    const int oc = oc0 + j, h = oc / HD, hd = oc % HD;
    const float bb_ = qk ? bias_k[oc] : bias_q[oc];
    const size_t headbase = (size_t)(b * NHH + h) * NN;
    short* base = (qk ? Kb : Qb) + (headbase) * 32 + hd;
    short* ObA = base + (size_t)((d0 + 0) * 16 + 4 * g) * 32;
    short* ObB = base + (size_t)((d0 + 1) * 16 + 4 * g) * 32;
#pragma unroll
    for (int r = 0; r < 4; ++r) {
        float vA = accA[r] + bb_, vB = accB[r] + bb_;
        if (!qk) { vA *= qs; vB *= qs; }
        ObA[r * 32] = f2bf(vA);
        ObB[r * 32] = f2bf(vB);
    }
    if (qk == 0) {
        short* Vb = Vtp + (size_t)(b * NHH + h) * (NN * 32);
        const int dh = hd >> 4, dj = hd & 15;
#pragma unroll
        for (int r = 0; r < 4; ++r) {
            int nA = d0 * 16 + 4 * g + r;
            int nB = nA + 16;
            int wA = vslot(nA & 63), wB = vslot(nB & 63);
            Vb[(nA >> 6) * 2048 + ((wA >> 5) * 2 + dh) * 512 + dj * 32 + (wA & 31)] = f2bf(avA[r]);
            Vb[(nB >> 6) * 2048 + ((wB >> 5) * 2 + dh) * 512 + dj * 32 + (wB & 31)] = f2bf(avB[r]);
        }
    }
    // pads once per token-block (z==0, oct==0; both qk waves)
    if (z == 0 && oct == 0) {
        const int n = (d0 + ((l >> 4) & 1)) * 16 + (l & 15);
        const s16x8 z8 = {0, 0, 0, 0, 0, 0, 0, 0};
        short* arr = qk ? Kb : Qb;
#pragma unroll
        for (int it = 0; it < 2; ++it) {
            int h2 = (l >> 5) + 2 * it;
            *(s16x8*)(arr + ((size_t)(b * NHH + h2) * NN + n) * 32 + 24) = z8;
        }
        const int h3 = qk * 2 + (l >> 5);     // qk=0: heads 0,1; qk=1: heads 2,3
        const int wN = vslot(n & 63);
        short* pb = Vtp + (size_t)(b * NHH + h3) * (NN * 32)
                  + (n >> 6) * 2048 + ((wN >> 5) * 2 + 1) * 512 + (wN & 31);
#pragma unroll
        for (int dj = 8; dj < 16; ++dj)
            pb[dj * 32] = 0;
    }
}

// MFMA flash attention — r22-proven (byte-identical): r10 math + exact
// rescale-skip; K-split x8, 8-way max-rebased LDS combine.
#define SOFTTILE(S0, S1, S2, S3, MX, LP, OA, OB, P0, P1) {                      \
    float v0 = fmaxf(fmaxf(S0[0], S0[1]), fmaxf(S0[2], S0[3]));                 \
    float v1 = fmaxf(fmaxf(S1[0], S1[1]), fmaxf(S1[2], S1[3]));                 \
    float v2 = fmaxf(fmaxf(S2[0], S2[1]), fmaxf(S2[2], S2[3]));                 \
    float v3 = fmaxf(fmaxf(S3[0], S3[1]), fmaxf(S3[2], S3[3]));                 \
    float vmx = fmaxf(fmaxf(v0, v1), fmaxf(v2, v3));                            \
    vmx = fmaxf(vmx, __shfl_xor(vmx, 16));                                      \
    vmx = fmaxf(vmx, __shfl_xor(vmx, 32));                                      \
    if (__any(vmx > MX)) {                                                      \
        float nm = fmaxf(MX, vmx);                                              \
        float sc = EXP2(MX - nm);                                               \
        MX = nm;                                                                \
        LP *= sc; OA *= sc; OB *= sc;                                           \
    }                                                                           \
    float p00 = EXP2(S0[0] - MX), p01 = EXP2(S0[1] - MX);                       \
    float p02 = EXP2(S0[2] - MX), p03 = EXP2(S0[3] - MX);                       \
    float p10 = EXP2(S1[0] - MX), p11 = EXP2(S1[1] - MX);                       \
    float p12 = EXP2(S1[2] - MX), p13 = EXP2(S1[3] - MX);                       \
    float p20 = EXP2(S2[0] - MX), p21 = EXP2(S2[1] - MX);                       \
    float p22 = EXP2(S2[2] - MX), p23 = EXP2(S2[3] - MX);                       \
    float p30 = EXP2(S3[0] - MX), p31 = EXP2(S3[1] - MX);                       \
    float p32 = EXP2(S3[2] - MX), p33 = EXP2(S3[3] - MX);                       \
    LP += (((p00 + p01) + (p02 + p03)) + ((p10 + p11) + (p12 + p13)))           \
        + (((p20 + p21) + (p22 + p23)) + ((p30 + p31) + (p32 + p33)));          \
    u32x4 w0_ = { bf16pk(p00, p01), bf16pk(p02, p03),                           \
                  bf16pk(p10, p11), bf16pk(p12, p13) };                         \
    u32x4 w1_ = { bf16pk(p20, p21), bf16pk(p22, p23),                           \
                  bf16pk(p30, p31), bf16pk(p32, p33) };                         \
    P0 = __builtin_bit_cast(s16x8, w0_);                                        \
    P1 = __builtin_bit_cast(s16x8, w1_);                                        \
}

__global__ __launch_bounds__(512) void attn_kernel(
        const short* __restrict__ Qb, const short* __restrict__ Kb,
        const short* __restrict__ Vtp, float* __restrict__ att) {
    __shared__ __align__(16) float comb[7][64][20];   // 35.8 KB
    const int bh = blockIdx.x & 15;            // pins bh pairs per XCD for L2 reuse
    const int q0 = (blockIdx.x >> 4) * 32;
    const int b = bh >> 2, h = bh & 3;
    const int tid = threadIdx.x, wvid = tid >> 6, l = tid & 63;
    const int j = l & 15, g = l >> 4;

    const s16x8 qf0 = *(const s16x8*)(Qb + ((size_t)bh * NN + q0 + j) * 32 + 8 * g);
    const s16x8 qf1 = *(const s16x8*)(Qb + ((size_t)bh * NN + q0 + 16 + j) * 32 + 8 * g);
    const short* Kbase = Kb  + (size_t)bh * NN * 32 + (size_t)j * 32 + 8 * g;
    const short* Vbase = Vtp + (size_t)bh * NN * 32 + (size_t)j * 32 + 8 * g;

    f32x4 oA0 = {0,0,0,0}, oB0 = {0,0,0,0};    // q-tile 0: O^T dims 4g.. / 16+4g..
    f32x4 oA1 = {0,0,0,0}, oB1 = {0,0,0,0};    // q-tile 1
    float mx0 = -1e30f, lp0 = 0.f, mx1 = -1e30f, lp1 = 0.f;
    const f32x4 z = {0,0,0,0};

    const int tbeg = wvid * (NN / 8);
    const int tend = tbeg + NN / 8;            // 320 keys, 5 tiles per wave

    for (int t0 = tbeg; t0 < tend; t0 += 64) {
        const short* kp = Kbase + (size_t)t0 * 32;
        s16x8 k0 = *(const s16x8*)(kp);
        s16x8 k1 = *(const s16x8*)(kp + 512);
        s16x8 k2 = *(const s16x8*)(kp + 1024);
        s16x8 k3 = *(const s16x8*)(kp + 1536);
        const short* vp = Vbase + (size_t)t0 * 32;     // tile base: t0/64*2048
        s16x8 vA0 = *(const s16x8*)(vp);               // (s0,d0)
        s16x8 vB0 = *(const s16x8*)(vp + 512);         // (s0,d1)
        s16x8 vA1 = *(const s16x8*)(vp + 1024);        // (s1,d0)
        s16x8 vB1 = *(const s16x8*)(vp + 1536);        // (s1,d1)

        f32x4 s0 = __builtin_amdgcn_mfma_f32_16x16x32_bf16(k0, qf0, z, 0, 0, 0);
        f32x4 s1 = __builtin_amdgcn_mfma_f32_16x16x32_bf16(k1, qf0, z, 0, 0, 0);
        f32x4 s2 = __builtin_amdgcn_mfma_f32_16x16x32_bf16(k2, qf0, z, 0, 0, 0);
        f32x4 s3 = __builtin_amdgcn_mfma_f32_16x16x32_bf16(k3, qf0, z, 0, 0, 0);
        s16x8 P00, P01;
        SOFTTILE(s0, s1, s2, s3, mx0, lp0, oA0, oB0, P00, P01)

        f32x4 t0s = __builtin_amdgcn_mfma_f32_16x16x32_bf16(k0, qf1, z, 0, 0, 0);
        f32x4 t1s = __builtin_amdgcn_mfma_f32_16x16x32_bf16(k1, qf1, z, 0, 0, 0);
        f32x4 t2s = __builtin_amdgcn_mfma_f32_16x16x32_bf16(k2, qf1, z, 0, 0, 0);
        f32x4 t3s = __builtin_amdgcn_mfma_f32_16x16x32_bf16(k3, qf1, z, 0, 0, 0);
        s16x8 P10, P11;
        SOFTTILE(t0s, t1s, t2s, t3s, mx1, lp1, oA1, oB1, P10, P11)

        oA0 = __builtin_amdgcn_mfma_f32_16x16x32_bf16(vA0, P00, oA0, 0, 0, 0);
        oA0 = __builtin_amdgcn_mfma_f32_16x16x32_bf16(vA1, P01, oA0, 0, 0, 0);
        oB0 = __builtin_amdgcn_mfma_f32_16x16x32_bf16(vB0, P00, oB0, 0, 0, 0);
        oB0 = __builtin_amdgcn_mfma_f32_16x16x32_bf16(vB1, P01, oB0, 0, 0, 0);
        oA1 = __builtin_amdgcn_mfma_f32_16x16x32_bf16(vA0, P10, oA1, 0, 0, 0);
        oA1 = __builtin_amdgcn_mfma_f32_16x16x32_bf16(vA1, P11, oA1, 0, 0, 0);
        oB1 = __builtin_amdgcn_mfma_f32_16x16x32_bf16(vB0, P10, oB1, 0, 0, 0);
        oB1 = __builtin_amdgcn_mfma_f32_16x16x32_bf16(vB1, P11, oB1, 0, 0, 0);
    }

    // row-sum lp across the 4 g-lanes
    lp0 += __shfl_xor(lp0, 16); lp0 += __shfl_xor(lp0, 32);
    lp1 += __shfl_xor(lp1, 16); lp1 += __shfl_xor(lp1, 32);

    if (wvid != 0) {
        float* cp = comb[wvid - 1][l];
        cp[0] = mx0; cp[1] = lp0; cp[2] = mx1; cp[3] = lp1;
        *(f32x4*)(cp + 4)  = oA0;
        *(f32x4*)(cp + 8)  = oB0;
        *(f32x4*)(cp + 12) = oA1;
        *(f32x4*)(cp + 16) = oB1;
    }
    __syncthreads();
    if (wvid != 0) return;

    // 8-way max-rebased combine
#pragma unroll
    for (int wv = 0; wv < 7; ++wv) {
        const float* cp = comb[wv][l];
        {
            float mb = cp[0], lb = cp[1];
            f32x4 oAb = *(const f32x4*)(cp + 4);
            f32x4 oBb = *(const f32x4*)(cp + 8);
            float mm = fmaxf(mx0, mb);
            float sa = EXP2(mx0 - mm), sb = EXP2(mb - mm);
            mx0 = mm;
            lp0 = lp0 * sa + lb * sb;
            oA0 = oA0 * sa + oAb * sb;
            oB0 = oB0 * sa + oBb * sb;
        }
        {
            float mb = cp[2], lb = cp[3];
            f32x4 oAb = *(const f32x4*)(cp + 12);
            f32x4 oBb = *(const f32x4*)(cp + 16);
            float mm = fmaxf(mx1, mb);
            float sa = EXP2(mx1 - mm), sb = EXP2(mb - mm);
            mx1 = mm;
            lp1 = lp1 * sa + lb * sb;
            oA1 = oA1 * sa + oAb * sb;
            oB1 = oB1 * sa + oBb * sb;
        }
    }

    const float rl0 = 1.f / lp0, rl1 = 1.f / lp1;
    f32x4 rA0 = oA0 * rl0, rB0 = oB0 * rl0;
    f32x4 rA1 = oA1 * rl1, rB1 = oB1 * rl1;

    float* op0 = att + ((size_t)b * NN + q0 + j) * CC + h * HD;
    float* op1 = att + ((size_t)b * NN + q0 + 16 + j) * CC + h * HD;
    *(f32x4*)(op0 + 4 * g) = rA0;
    *(f32x4*)(op1 + 4 * g) = rA1;
    if (g < 2) {
        *(f32x4*)(op0 + 16 + 4 * g) = rB0;
        *(f32x4*)(op1 + 16 + 4 * g) = rB1;
    }
}

// MFMA out-projection — r16 (proven, byte-identical).
__global__ __launch_bounds__(256) void proj_kernel(
        const float* __restrict__ att, const short* __restrict__ wo_b,
        const float* __restrict__ bo, float* __restrict__ out) {
    __shared__ __align__(16) short als[64 * 104];
    const int t0 = blockIdx.x * 64;
    const int tid = threadIdx.x;
#pragma unroll
    for (int k = 0; k < 6; ++k) {
        int c = tid + k * 256;                      // 1536 chunks
        int row = c / 24, ic0 = (c % 24) * 4;
        f32x4 v = *(const f32x4*)(att + (size_t)(t0 + row) * CC + ic0);
        u32x2 o = { bf16pk(v[0], v[1]), bf16pk(v[2], v[3]) };
        *(u32x2*)&als[row * 104 + ic0] = o;
    }
    __syncthreads();

    const int w = tid >> 6, l = tid & 63;
    const int j = l & 15, g = l >> 4;
    const short* ap = &als[(w * 16 + j) * 104 + 8 * g];
    s16x8 a0 = *(const s16x8*)(ap);
    s16x8 a1 = *(const s16x8*)(ap + 32);
    s16x8 a2 = *(const s16x8*)(ap + 64);
    const f32x4 zz = {0, 0, 0, 0};
    float* ob = out + (size_t)(t0 + w * 16 + 4 * g) * CC + j;
#pragma unroll
    for (int oct = 0; oct < 6; ++oct) {
        const short* wp = wo_b + oct * 3 * 512 + j * 32 + 8 * g;
        f32x4 acc = zz;
        acc = __builtin_amdgcn_mfma_f32_16x16x32_bf16(a0, *(const s16x8*)(wp),        acc, 0, 0, 0);
        acc = __builtin_amdgcn_mfma_f32_16x16x32_bf16(a1, *(const s16x8*)(wp + 512),  acc, 0, 0, 0);
        acc = __builtin_amdgcn_mfma_f32_16x16x32_bf16(a2, *(const s16x8*)(wp + 1024), acc, 0, 0, 0);
        const float bb = bo[oct * 16 + j];
#pragma unroll
        for (int r = 0; r < 4; ++r)
            ob[(size_t)r * CC + oct * 16] = acc[r] + bb;
    }
}

extern "C" void kernel_launch(void* const* d_in, const int* in_sizes, int n_in,
                              void* d_out, int out_size, void* d_ws, size_t ws_size,
                              hipStream_t stream) {
    const float* x     = (const float*)d_in[0];
    const float* sg    = (const float*)d_in[1];
    const float* wq    = (const float*)d_in[2];
    const float* bnq_g = (const float*)d_in[3];
    const float* bnq_b = (const float*)d_in[4];
    const float* bnq_m = (const float*)d_in[5];
    const float* bnq_v = (const float*)d_in[6];
    const float* wk    = (const float*)d_in[7];
    const float* bnk_g = (const float*)d_in[8];
    const float* bnk_b = (const float*)d_in[9];
    const float* bnk_m = (const float*)d_in[10];
    const float* bnk_v = (const float*)d_in[11];
    const float* wv    = (const float*)d_in[12];
    const float* wo    = (const float*)d_in[13];
    const float* bo    = (const float*)d_in[14];

    float* ws = (float*)d_ws;
    short* wq_b   = (short*)(ws + WS_WQ);
    short* wk_b   = (short*)(ws + WS_WK);
    short* wv_b   = (short*)(ws + WS_WV);
    float* bias_q = ws + WS_BQ;
    float* bias_k = ws + WS_BK;
    float* attw   = ws + WS_ATT;
    short* Qb     = (short*)(ws + WS_QB);
    short* Kb     = (short*)(ws + WS_KB);
    short* Vtp    = (short*)(ws + WS_VT);
    short* wo_b   = (short*)(ws + WS_WO);

    prep_all<<<dim3(CC, 3), dim3(128), 0, stream>>>(
        wq, bnq_g, bnq_b, bnq_m, bnq_v,
        wk, bnk_g, bnk_b, bnk_m, bnk_v,
        wv, wo, wq_b, wk_b, wv_b, wo_b, bias_q, bias_k);

    qkv_conv<<<dim3(DEPTH / 2, BB, 2), dim3(384), 0, stream>>>(
        x, wq_b, wk_b, wv_b, bias_q, bias_k, sg, Qb, Kb, Vtp);

    attn_kernel<<<dim3(NN / 32 * 16), dim3(512), 0, stream>>>(Qb, Kb, Vtp, attw);

    proj_kernel<<<dim3(BB * NN / 64), dim3(256), 0, stream>>>(attw, wo_b, bo, (float*)d_out);
}